// Round 10
// baseline (152.609 us; speedup 1.0000x reference)
//
#include <hip/hip_runtime.h>

#define NS   64      // state dim
#define CH   128     // channels
#define LSEQ 4096    // sequence length
#define NB   16      // batch
#define SCH  64      // chunk size
#define MCH  64      // number of chunks (LSEQ/SCH)
#define ST   68      // padded LDS row stride (68*4 = 272B, 16B-aligned)
#define CP   128     // C^T pool stride (reads are uniform-row -> conflict-free)

// ws float offsets
#define WS_ABAR 0          // 64*64 A_bar row-major
#define WS_A16  4096       // 64*64 A_bar^16
#define WS_VS   8192       // 64*64 vs[j*64+i]
#define WS_BBAR 12288      // 64

// X0 stash in d_out: slot (b,m) later written only by k_main block (m,b).
#define X0_IDX(b, m) (((size_t)(b) * CH) * LSEQ + (size_t)(m) * SCH)

// k_main2 pool aliasing (floats): phase1 scratch + A16, then C^T (8192 f)
#define P_VSS  0
#define P_XCW  1024
#define P_XBS  1280
#define P_PLE  1536
#define P_PART 1792
#define P_A16  2048

#define FMA44(av, bv)                                                          \
    a0.x += av.x * bv.x; a0.y += av.x * bv.y; a0.z += av.x * bv.z; a0.w += av.x * bv.w; \
    a1.x += av.y * bv.x; a1.y += av.y * bv.y; a1.z += av.y * bv.z; a1.w += av.y * bv.w; \
    a2.x += av.z * bv.x; a2.y += av.z * bv.y; a2.z += av.z * bv.z; a2.w += av.z * bv.w; \
    a3.x += av.w * bv.x; a3.y += av.w * bv.y; a3.z += av.w * bv.z; a3.w += av.w * bv.w;

// NOTE (lower-triangularity): HiPPO A is lower-triangular, hence A_bar and all
// its powers are EXACTLY lower-triangular (the substitution produces exact 0.0f
// above the diagonal). In C = A*A, terms with k > i vanish, so k-loops truncate
// at the tile's last row +1. Upper tiles compute exact zeros and still write
// them -> no consumer change needed.

// 64x64 lower-tri matrix square on 256 threads (e = 0..255): (cm,cmt) -> (nm[,nmt]).
// cmt[k][i] = cm[i][k]. WT=false skips the transposed copy.
template<bool WT>
__device__ __forceinline__ void mm_square(const float* __restrict__ cm,
                                          const float* __restrict__ cmt,
                                          float* __restrict__ nm,
                                          float* __restrict__ nmt, int e) {
    const int l = e & 63;
    const int si0 = 16 * ((e >> 6) & 3) + 4 * (l >> 4);
    const int sj0 = 4 * (l & 15);
    const int kmax = si0 + 4;   // lower-tri: A[i][k]=0 for k>i (exact)
    float4 a0 = {0,0,0,0}, a1 = {0,0,0,0}, a2 = {0,0,0,0}, a3 = {0,0,0,0};
    for (int k = 0; k < kmax; k += 4) {
        float4 av0 = *(const float4*)&cmt[(k + 0) * ST + si0];
        float4 bv0 = *(const float4*)&cm [(k + 0) * ST + sj0];
        float4 av1 = *(const float4*)&cmt[(k + 1) * ST + si0];
        float4 bv1 = *(const float4*)&cm [(k + 1) * ST + sj0];
        float4 av2 = *(const float4*)&cmt[(k + 2) * ST + si0];
        float4 bv2 = *(const float4*)&cm [(k + 2) * ST + sj0];
        float4 av3 = *(const float4*)&cmt[(k + 3) * ST + si0];
        float4 bv3 = *(const float4*)&cm [(k + 3) * ST + sj0];
        FMA44(av0, bv0)
        FMA44(av1, bv1)
        FMA44(av2, bv2)
        FMA44(av3, bv3)
    }
    *(float4*)&nm[(si0 + 0) * ST + sj0] = a0;
    *(float4*)&nm[(si0 + 1) * ST + sj0] = a1;
    *(float4*)&nm[(si0 + 2) * ST + sj0] = a2;
    *(float4*)&nm[(si0 + 3) * ST + sj0] = a3;
    if (WT) {
        float4 t0 = {a0.x, a1.x, a2.x, a3.x};
        float4 t1 = {a0.y, a1.y, a2.y, a3.y};
        float4 t2 = {a0.z, a1.z, a2.z, a3.z};
        float4 t3 = {a0.w, a1.w, a2.w, a3.w};
        *(float4*)&nmt[(sj0 + 0) * ST + si0] = t0;
        *(float4*)&nmt[(sj0 + 1) * ST + si0] = t1;
        *(float4*)&nmt[(sj0 + 2) * ST + si0] = t2;
        *(float4*)&nmt[(sj0 + 3) * ST + si0] = t3;
    }
}

// 64x64 lower-tri square on ALL 1024 threads: 4-row x 1-col tile per thread.
// si0 is wave-uniform -> the A-operand float4 load is a broadcast (conflict-free,
// one LDS op per wave); per-wave FMA halves vs the 512-thread 4x2 tiling.
__device__ __forceinline__ void mm_sq41(const float* __restrict__ cm,
                                        const float* __restrict__ cmt,
                                        float* __restrict__ nm,
                                        float* __restrict__ nmt, int tid) {
    const int si0 = 4 * (tid >> 6);     // 16 i-quads, uniform per wave
    const int j   = tid & 63;
    const int kmax = si0 + 4;           // lower-tri truncation (exact)
    float a0 = 0.f, a1 = 0.f, a2 = 0.f, a3 = 0.f;
#pragma unroll 4
    for (int k = 0; k < kmax; ++k) {
        float4 av = *(const float4*)&cmt[k * ST + si0];   // broadcast
        float  bv = cm[k * ST + j];
        a0 = fmaf(av.x, bv, a0); a1 = fmaf(av.y, bv, a1);
        a2 = fmaf(av.z, bv, a2); a3 = fmaf(av.w, bv, a3);
    }
    nm[(si0 + 0) * ST + j] = a0;
    nm[(si0 + 1) * ST + j] = a1;
    nm[(si0 + 2) * ST + j] = a2;
    nm[(si0 + 3) * ST + j] = a3;
    float4 t = {a0, a1, a2, a3};
    *(float4*)&nmt[j * ST + si0] = t;
}

// vs-expansion, (i-quad, j) shape: VT[:, mexp+j] += cmt-power * VT[:, j].
// Caller guards thread range. iq in [0,16), j in [0,nj).
__device__ __forceinline__ void vs_expand1(const float* __restrict__ cmt,
                                           float* __restrict__ VT,
                                           int iq, int j, int mexp) {
    const int i0 = 4 * iq;
    float4 acc = {0,0,0,0};
#pragma unroll 8
    for (int k = 0; k < NS; ++k) {
        float4 av = *(const float4*)&cmt[k * ST + i0];
        float bk = VT[k * ST + j];
        acc.x += av.x * bk; acc.y += av.y * bk;
        acc.z += av.z * bk; acc.w += av.w * bk;
    }
    VT[(i0 + 0) * ST + mexp + j] = acc.x;
    VT[(i0 + 1) * ST + mexp + j] = acc.y;
    VT[(i0 + 2) * ST + mexp + j] = acc.z;
    VT[(i0 + 3) * ST + mexp + j] = acc.w;
}

// PQ step on 256 threads: outb[g] = A64*xle[4g+r0] + xle[4g+r0+1]
// Acol[k*ST+i] = A64[i][k].
__device__ __forceinline__ void pq_step(const float* __restrict__ Acol,
                                        const float* __restrict__ xle,
                                        float* __restrict__ outb, int r0, int e) {
    const int g = e >> 4, i0 = 4 * (e & 15);
    const float* bp = &xle[(4 * g + r0) * NS];
    float4 acc = *(const float4*)&xle[(4 * g + r0 + 1) * NS + i0];
#pragma unroll 8
    for (int k = 0; k < NS; ++k) {
        float4 av = *(const float4*)&Acol[k * ST + i0];
        float bk = bp[k];
        acc.x = fmaf(av.x, bk, acc.x); acc.y = fmaf(av.y, bk, acc.y);
        acc.z = fmaf(av.z, bk, acc.z); acc.w = fmaf(av.w, bk, acc.w);
    }
    *(float4*)&outb[g * ST + i0] = acc;
}

// Y step on 512 threads (float2 tiles): Y[g] = A128*P[g] + Q[g]
__device__ __forceinline__ void y_step512(const float* __restrict__ A128col,
                                          const float* __restrict__ P,
                                          const float* __restrict__ Q,
                                          float* __restrict__ Y, int e) {
    const int g = e >> 5, c0 = 2 * (e & 31);
    const float* bp = &P[g * ST];            // 32-lane broadcast
    float2 acc = *(const float2*)&Q[g * ST + c0];
#pragma unroll 8
    for (int k = 0; k < NS; ++k) {
        float2 av = *(const float2*)&A128col[k * ST + c0];
        float bk = bp[k];
        acc.x = fmaf(av.x, bk, acc.x); acc.y = fmaf(av.y, bk, acc.y);
    }
    *(float2*)&Y[g * ST + c0] = acc;
}

// Interior expansion on 256 threads: stash[4g+r] = A64*stash[4g+r-1] + xle[4g+r-1].
__device__ __forceinline__ void inner_step(const float* __restrict__ Acol,
                                           const float* __restrict__ xle,
                                           float* __restrict__ stash, int r, int e) {
    const int g = e >> 4, i0 = 4 * (e & 15);
    const int mp = 4 * g + r - 1;
    float4 acc = *(const float4*)&xle[mp * NS + i0];
    const float* xp = &stash[mp * ST];
#pragma unroll 8
    for (int k = 0; k < NS; ++k) {
        float4 av = *(const float4*)&Acol[k * ST + i0];
        float xk = xp[k];
        acc.x = fmaf(av.x, xk, acc.x); acc.y = fmaf(av.y, xk, acc.y);
        acc.z = fmaf(av.z, xk, acc.z); acc.w = fmaf(av.w, xk, acc.w);
    }
    *(float4*)&stash[(mp + 1) * ST + i0] = acc;
}

// Interior expansion on 512 threads (float2 tiles), r fixed.
__device__ __forceinline__ void inner512(const float* __restrict__ Acol,
                                         const float* __restrict__ xle,
                                         float* __restrict__ stash, int r, int e) {
    const int g = e >> 5, c0 = 2 * (e & 31);
    const int mp = 4 * g + r - 1;
    float2 acc = *(const float2*)&xle[mp * NS + c0];
    const float* xp = &stash[mp * ST];       // 32-lane broadcast
#pragma unroll 8
    for (int k = 0; k < NS; ++k) {
        float2 av = *(const float2*)&Acol[k * ST + c0];
        float xk = xp[k];
        acc.x = fmaf(av.x, xk, acc.x); acc.y = fmaf(av.y, xk, acc.y);
    }
    *(float2*)&stash[(mp + 1) * ST + c0] = acc;
}

// E1-upper on 256 threads: stash[4g+2] = A128*stash[4g] + P[g]
__device__ __forceinline__ void e1u_step(const float* __restrict__ A128col,
                                         const float* __restrict__ P,
                                         float* __restrict__ stash, int e) {
    const int g = e >> 4, i0 = 4 * (e & 15);
    const float* xp = &stash[(4 * g) * ST];
    float4 acc = *(const float4*)&P[g * ST + i0];
#pragma unroll 8
    for (int k = 0; k < NS; ++k) {
        float4 av = *(const float4*)&A128col[k * ST + i0];
        float xk = xp[k];
        acc.x = fmaf(av.x, xk, acc.x); acc.y = fmaf(av.y, xk, acc.y);
        acc.z = fmaf(av.z, xk, acc.z); acc.w = fmaf(av.w, xk, acc.w);
    }
    *(float4*)&stash[(4 * g + 2) * ST + i0] = acc;
}

// ---------------------------------------------------------------------------
// K1: setup + shortened boundary scan, now 1024 threads.
//  - levels 1-4: 1024-thread square (4x1 tiles, broadcast A-operand)
//  - s=6 expansion widened to 512 threads (1 col/thread)
//  - uT staging & X0 store single-pass
//  - all other phases keep their proven 256/512-thread mappings
//    (waves 8-15 idle there; every thread reaches every barrier)
// ---------------------------------------------------------------------------
__global__ __launch_bounds__(1024) void k_sb(const float* __restrict__ u,
                                             const float* __restrict__ A,
                                             const float* __restrict__ Bv,
                                             const float* __restrict__ dtp,
                                             float* __restrict__ ws,
                                             float* __restrict__ out) {
    __shared__ __align__(16) float Mrow[NS * ST];        // power ping-pong (row)
    __shared__ __align__(16) float Mcol[(NS + 1) * ST];  // transposed; row 64 = B_bar
    __shared__ __align__(16) float Nrow[NS * ST];
    __shared__ __align__(16) float Ncol[NS * ST];
    __shared__ __align__(16) float VT[NS * ST];          // vs cols, then A^256 rows
    __shared__ __align__(16) float uT[NS * ST];          // uT, then X0 stash [m*ST+i]
    __shared__ __align__(16) float vsS[NS * NS];         // vs[j][i], then P/Q/Y bufs
    __shared__ __align__(16) float xleS[MCH * NS];       // xle[m][i]
    __shared__ __align__(16) float bcol[NS];
    __shared__ float rdiag[NS], xcS[NS];
    float* const stash = uT;              // X0 stash (uT dead after xle)
    float* const HbP = vsS;               // P buffer (vsS dead after xle)
    float* const HbQ = vsS + 16 * ST;     // Q buffer
    float* const HbY = vsS + 32 * ST;     // Y buffer (48*ST = 3264 <= 4096 ok)
    const int tid = threadIdx.x;
    const int b = blockIdx.x;
    const float dt = dtp[0];
    const float hdt = 0.5f * dt;

    // A-setup (no zero-init: every read location is written first)
    for (int o = tid; o < NS * NS; o += 1024) {
        int i = o >> 6, k = o & 63;
        float a = A[o];
        float d = (i == k) ? 1.0f : 0.0f;
        Nrow[i * ST + k] = d - hdt * a;   // T1
        Ncol[k * ST + i] = d + hdt * a;   // T2^T
    }
    if (tid < NS) {
        bcol[tid]  = dt * Bv[tid];
        rdiag[tid] = 1.0f / (1.0f - hdt * A[tid * NS + tid]);
    }
    __syncthreads();

    // stage u transposed early: uT[jj][m] = u[b][m*64 + 63-jj] (1 float4/thread)
    {
        const int jj = tid & 63;
        const int m0 = 4 * (tid >> 6);   // 0,4,...,60
        float4 v;
        v.x = u[b * LSEQ + (m0 + 0) * SCH + 63 - jj];
        v.y = u[b * LSEQ + (m0 + 1) * SCH + 63 - jj];
        v.z = u[b * LSEQ + (m0 + 2) * SCH + 63 - jj];
        v.w = u[b * LSEQ + (m0 + 3) * SCH + 63 - jj];
        *(float4*)&uT[jj * ST + m0] = v;
    }

    // forward substitution, column j in registers (lane j; tid==64 -> B_bar)
    if (tid <= NS) {
        float xr[NS];
        const float* t2b = (tid < NS) ? &Ncol[tid * ST] : bcol;
#pragma unroll
        for (int I = 0; I < 16; ++I) {
            const int i0 = 4 * I;
            float4 t2 = *(const float4*)&t2b[i0];
            float a0 = t2.x, a1 = t2.y, a2 = t2.z, a3 = t2.w;
#pragma unroll
            for (int k = 0; k < i0; k += 4) {
                float4 n0 = *(const float4*)&Nrow[(i0 + 0) * ST + k];
                float4 n1 = *(const float4*)&Nrow[(i0 + 1) * ST + k];
                float4 n2 = *(const float4*)&Nrow[(i0 + 2) * ST + k];
                float4 n3 = *(const float4*)&Nrow[(i0 + 3) * ST + k];
                a0 -= n0.x * xr[k] + n0.y * xr[k + 1] + n0.z * xr[k + 2] + n0.w * xr[k + 3];
                a1 -= n1.x * xr[k] + n1.y * xr[k + 1] + n1.z * xr[k + 2] + n1.w * xr[k + 3];
                a2 -= n2.x * xr[k] + n2.y * xr[k + 1] + n2.z * xr[k + 2] + n2.w * xr[k + 3];
                a3 -= n3.x * xr[k] + n3.y * xr[k + 1] + n3.z * xr[k + 2] + n3.w * xr[k + 3];
            }
            float4 rd  = *(const float4*)&rdiag[i0];
            float4 nb1 = *(const float4*)&Nrow[(i0 + 1) * ST + i0];
            float4 nb2 = *(const float4*)&Nrow[(i0 + 2) * ST + i0];
            float4 nb3 = *(const float4*)&Nrow[(i0 + 3) * ST + i0];
            float x0 = a0 * rd.x;
            float x1 = (a1 - nb1.x * x0) * rd.y;
            float x2 = (a2 - nb2.x * x0 - nb2.y * x1) * rd.z;
            float x3 = (a3 - nb3.x * x0 - nb3.y * x1 - nb3.z * x2) * rd.w;
            xr[i0 + 0] = x0; xr[i0 + 1] = x1; xr[i0 + 2] = x2; xr[i0 + 3] = x3;
        }
        float* xrow = &Mcol[tid * ST];
#pragma unroll
        for (int k = 0; k < NS; k += 4) {
            float4 v = {xr[k], xr[k + 1], xr[k + 2], xr[k + 3]};
            *(float4*)&xrow[k] = v;
        }
    }
    __syncthreads();

    // transpose Mcol -> Mrow; b0 stores ABAR, b1 stores BBAR; seed VT col 0
    if (tid < 256) {
        const int i0 = 4 * (tid >> 4), j0 = 4 * (tid & 15);
        float4 r0 = *(const float4*)&Mcol[(j0 + 0) * ST + i0];
        float4 r1 = *(const float4*)&Mcol[(j0 + 1) * ST + i0];
        float4 r2 = *(const float4*)&Mcol[(j0 + 2) * ST + i0];
        float4 r3 = *(const float4*)&Mcol[(j0 + 3) * ST + i0];
        float4 w0 = {r0.x, r1.x, r2.x, r3.x};
        float4 w1 = {r0.y, r1.y, r2.y, r3.y};
        float4 w2 = {r0.z, r1.z, r2.z, r3.z};
        float4 w3 = {r0.w, r1.w, r2.w, r3.w};
        *(float4*)&Mrow[(i0 + 0) * ST + j0] = w0;
        *(float4*)&Mrow[(i0 + 1) * ST + j0] = w1;
        *(float4*)&Mrow[(i0 + 2) * ST + j0] = w2;
        *(float4*)&Mrow[(i0 + 3) * ST + j0] = w3;
        if (b == 0) {
            *(float4*)&ws[WS_ABAR + (i0 + 0) * NS + j0] = w0;
            *(float4*)&ws[WS_ABAR + (i0 + 1) * NS + j0] = w1;
            *(float4*)&ws[WS_ABAR + (i0 + 2) * NS + j0] = w2;
            *(float4*)&ws[WS_ABAR + (i0 + 3) * NS + j0] = w3;
        }
    }
    if (b == 1 && tid < 16)
        *(float4*)&ws[WS_BBAR + 4 * tid] = *(const float4*)&Mcol[NS * ST + 4 * tid];
    if (tid < NS) VT[tid * ST + 0] = Mcol[NS * ST + tid];
    __syncthreads();

    // 6 levels of squaring with vs-expansion.
    //  s<=4: all 1024 threads square (4x1, broadcast A), inline expansion.
    //  s=5: 256-thread square || 256-thread expansion.
    //  s=6: 256-thread square || 512-thread expansion (1 col/thread).
    float *cm = Mrow, *cmt = Mcol, *nm = Nrow, *nmt = Ncol;
    for (int s = 1; s <= 6; ++s) {
        if (s <= 4) {
            mm_sq41(cm, cmt, nm, nmt, tid);
            const int mexp = 1 << (s - 1);   // 1,2,4,8 = nj
            if (tid < 16 * mexp) {
                vs_expand1(cmt, VT, tid & 15, tid >> 4, mexp);
            }
        } else if (tid < 256) {
            mm_square<true>(cm, cmt, nm, nmt, tid);
        } else {
            const int e = tid - 256;
            if (s == 5) {
                if (e < 256) vs_expand1(cmt, VT, e & 15, e >> 4, 16);
            } else {
                if (e < 512) vs_expand1(cmt, VT, e & 15, e >> 4, 32);
            }
        }
        __syncthreads();
        { float* t = cm; cm = nm; nm = t; t = cmt; cmt = nmt; nmt = t; }
        if (s == 4 && b == 2) {   // cm == A^16
            for (int o = tid; o < (NS * NS) / 4; o += 1024) {
                int r = o >> 4, c4 = (o & 15) * 4;
                *(float4*)&ws[WS_A16 + r * NS + c4] = *(const float4*)&cm[r * ST + c4];
            }
        }
    }
    // (Mrow, Mcol) = A^64 pair; (Nrow, Ncol) = A^32 (dead).

    // Phase A: tid<256: VT -> vsS transpose (+ b3 VS store).
    //          tid in [256,512): A^128 square (M-pair -> N-pair).
    if (tid < 256) {
        const int i0 = 4 * (tid >> 4), j0 = 4 * (tid & 15);
        float4 v0 = *(const float4*)&VT[(i0 + 0) * ST + j0];
        float4 v1 = *(const float4*)&VT[(i0 + 1) * ST + j0];
        float4 v2 = *(const float4*)&VT[(i0 + 2) * ST + j0];
        float4 v3 = *(const float4*)&VT[(i0 + 3) * ST + j0];
        float4 w0 = {v0.x, v1.x, v2.x, v3.x};
        float4 w1 = {v0.y, v1.y, v2.y, v3.y};
        float4 w2 = {v0.z, v1.z, v2.z, v3.z};
        float4 w3 = {v0.w, v1.w, v2.w, v3.w};
        *(float4*)&vsS[(j0 + 0) * NS + i0] = w0;
        *(float4*)&vsS[(j0 + 1) * NS + i0] = w1;
        *(float4*)&vsS[(j0 + 2) * NS + i0] = w2;
        *(float4*)&vsS[(j0 + 3) * NS + i0] = w3;
        if (b == 3) {
            *(float4*)&ws[WS_VS + (j0 + 0) * NS + i0] = w0;
            *(float4*)&ws[WS_VS + (j0 + 1) * NS + i0] = w1;
            *(float4*)&ws[WS_VS + (j0 + 2) * NS + i0] = w2;
            *(float4*)&ws[WS_VS + (j0 + 3) * NS + i0] = w3;
        }
    } else if (tid < 512) {
        mm_square<true>(Mrow, Mcol, Nrow, Ncol, tid - 256);   // A^128
    }
    __syncthreads();

    // Phase B: tid<256: xle[m][i] = sum_j vs[j][i] * uT[j][m].
    //          tid in [256,512): A^256 square, rows only -> VT (VT dead).
    if (tid < 256) {
        const int ig = tid & 15, mg = tid >> 4;
        float4 a0 = {0,0,0,0}, a1 = {0,0,0,0}, a2 = {0,0,0,0}, a3 = {0,0,0,0};
#pragma unroll 4
        for (int j = 0; j < NS; j += 2) {
            float4 am  = *(const float4*)&uT[j * ST + 4 * mg];
            float4 bi  = *(const float4*)&vsS[j * NS + 4 * ig];
            float4 am2 = *(const float4*)&uT[(j + 1) * ST + 4 * mg];
            float4 bi2 = *(const float4*)&vsS[(j + 1) * NS + 4 * ig];
            FMA44(am, bi)
            FMA44(am2, bi2)
        }
        *(float4*)&xleS[(4 * mg + 0) * NS + 4 * ig] = a0;
        *(float4*)&xleS[(4 * mg + 1) * NS + 4 * ig] = a1;
        *(float4*)&xleS[(4 * mg + 2) * NS + 4 * ig] = a2;
        *(float4*)&xleS[(4 * mg + 3) * NS + 4 * ig] = a3;
    } else if (tid < 512) {
        mm_square<false>(Nrow, Ncol, VT, VT, tid - 256);      // A^256 rows
    }
    __syncthreads();

    // Phase C1: P[g] = A64*xle_{4g} + xle_{4g+1}  (tid<256)
    //           Q[g] = A64*xle_{4g+2} + xle_{4g+3} (tid in [256,512))
    // tid<64 inits scan state (stash=uT is dead).
    if (tid < 256) pq_step(Mcol, xleS, HbP, 0, tid);
    else if (tid < 512) pq_step(Mcol, xleS, HbQ, 2, tid - 256);
    if (tid < 64) { xcS[tid] = 0.f; stash[tid] = 0.f; }   // Z_0 = X0_0 = 0
    __syncthreads();

    // Phase C2: Y[g] = A128*P[g] + Q[g] on 512 threads (float2 tiles).
    if (tid < 512) y_step512(Ncol, HbP, HbQ, HbY, tid);
    __syncthreads();

    // Phase D: 15-step serial scan  Z_{g+1} = A256 * Z_g + Y_g.
    // SINGLE WAVE: lane i holds row i of A^256 in 16 float4 regs; xc is read
    // from xcS via uniform (broadcast, conflict-free) float4 loads; Y vectors
    // preloaded into registers. No barriers in the loop.
    if (tid < 64) {
        const int i = tid;
        float4 arow[16];
#pragma unroll
        for (int c = 0; c < 16; ++c)
            arow[c] = *(const float4*)&VT[i * ST + 4 * c];
        float yv[15];
#pragma unroll
        for (int g = 0; g < 15; ++g) yv[g] = HbY[g * ST + i];
        for (int g = 0; g < 15; ++g) {
            float a0 = 0.f, a1 = 0.f, a2 = 0.f, a3 = 0.f;
#pragma unroll
            for (int c = 0; c < 16; ++c) {
                float4 xv = *(const float4*)&xcS[4 * c];
                a0 = fmaf(arow[c].x, xv.x, a0);
                a1 = fmaf(arow[c].y, xv.y, a1);
                a2 = fmaf(arow[c].z, xv.z, a2);
                a3 = fmaf(arow[c].w, xv.w, a3);
            }
            const float xn = ((a0 + a1) + (a2 + a3)) + yv[g];
            xcS[i] = xn;                       // next iter reads via broadcast
            stash[(4 * g + 4) * ST + i] = xn;  // X0_{4(g+1)} (fire-and-forget)
        }
    }
    __syncthreads();

    // Phase E1: stash[4g+1] = A64*stash[4g] + xle_{4g}      (tid<256)
    //           stash[4g+2] = A128*stash[4g] + P[g]         (tid in [256,512))
    if (tid < 256) inner_step(Mcol, xleS, stash, 1, tid);
    else if (tid < 512) e1u_step(Ncol, HbP, stash, tid - 256);
    __syncthreads();

    // Phase E2: stash[4g+3] = A64*stash[4g+2] + xle_{4g+2}  (512, float2)
    if (tid < 512) inner512(Mcol, xleS, stash, 3, tid);
    __syncthreads();

    // Phase F: bulk-store X0 (single drain; 1 float4/thread)
    {
        const int m = tid >> 4, t4 = (tid & 15) * 4;
        float4 o1 = *(const float4*)&stash[m * ST + t4];
        *(float4*)&out[X0_IDX(b, m) + t4] = o1;
    }
}

// ---------------------------------------------------------------------------
// K2: main. (round-9 kernel, unchanged — row-per-lane recurrence proven)
// ---------------------------------------------------------------------------
__global__ __launch_bounds__(256) void k_main2(const float* __restrict__ u,
                                               const float* __restrict__ Cm,
                                               const float* __restrict__ Dv,
                                               const float* __restrict__ ws,
                                               float* __restrict__ out) {
    __shared__ __align__(16) float Xl[NS * ST];     // A_bar staging, then X[i][t]
    __shared__ __align__(16) float pool[NS * CP];   // phase1 scratch+A16, then C^T
    __shared__ float uS[SCH], DS[CH], bbS[NS];
    const int m = blockIdx.x, b = blockIdx.y;
    const int tid = threadIdx.x;
    const int l = tid & 63, w = tid >> 6;

    for (int o = tid; o < (NS * NS) / 4; o += 256) {
        int r = o >> 4, c4 = (o & 15) * 4;
        *(float4*)&Xl[r * ST + c4]          = *(const float4*)&ws[WS_ABAR + r * NS + c4];
        *(float4*)&pool[P_A16 + r * NS + c4] = *(const float4*)&ws[WS_A16 + r * NS + c4];
    }
    for (int o = tid; o < 16 * NS; o += 256) pool[P_VSS + o] = ws[WS_VS + o];
    if (tid < NS) {
        uS[tid]  = u[b * LSEQ + m * SCH + tid];
        bbS[tid] = ws[WS_BBAR + tid];
        pool[P_XBS + tid] = out[X0_IDX(b, m) + tid];
    }
    if (tid < CH) DS[tid] = Dv[tid];
    __syncthreads();

    // Row-per-lane A_bar: lane l holds row l (16 float4 = 64 VGPR).
    float4 arow[16];
#pragma unroll
    for (int c = 0; c < 16; ++c)
        arow[c] = *(const float4*)&Xl[l * ST + 4 * c];
    const float bbl = bbS[l];
    float ur[16];
#pragma unroll
    for (int s = 0; s < 16; ++s) ur[s] = uS[16 * w + s];
    float4 a16r[4];
#pragma unroll
    for (int kq = 0; kq < 4; ++kq)
        a16r[kq] = *(const float4*)&pool[P_A16 + l * NS + 16 * w + 4 * kq];

    {
        float s = 0.f;
#pragma unroll
        for (int j = 0; j < 16; ++j) s += pool[P_VSS + j * NS + l] * uS[16 * w + 15 - j];
        pool[P_PLE + w * NS + l] = s;
    }
    __syncthreads();

    for (int p = 1; p < 4; ++p) {
        float4 x0q = *(const float4*)&pool[P_XBS + (p - 1) * NS + 16 * w + 0];
        float4 x1q = *(const float4*)&pool[P_XBS + (p - 1) * NS + 16 * w + 4];
        float4 x2q = *(const float4*)&pool[P_XBS + (p - 1) * NS + 16 * w + 8];
        float4 x3q = *(const float4*)&pool[P_XBS + (p - 1) * NS + 16 * w + 12];
        float s = a16r[0].x * x0q.x + a16r[0].y * x0q.y + a16r[0].z * x0q.z + a16r[0].w * x0q.w
                + a16r[1].x * x1q.x + a16r[1].y * x1q.y + a16r[1].z * x1q.z + a16r[1].w * x1q.w
                + a16r[2].x * x2q.x + a16r[2].y * x2q.y + a16r[2].z * x2q.z + a16r[2].w * x2q.w
                + a16r[3].x * x3q.x + a16r[3].y * x3q.y + a16r[3].z * x3q.z + a16r[3].w * x3q.w;
        pool[P_PART + w * NS + l] = s;
        __syncthreads();
        if (w == 0) {
            float xn = pool[P_PART + l] + pool[P_PART + NS + l] + pool[P_PART + 2 * NS + l]
                     + pool[P_PART + 3 * NS + l] + pool[P_PLE + (p - 1) * NS + l];
            pool[P_XBS + p * NS + l] = xn;
        }
        __syncthreads();
    }

    // Within-paragraph recurrence, row-per-lane (wave-private LDS slice).
    pool[P_XCW + w * NS + l] = pool[P_XBS + w * NS + l];
    for (int s = 0; s < 16; ++s) {
        const int t = 16 * w + s;
        float a0 = 0.f, a1 = 0.f, a2 = 0.f, a3 = 0.f;
#pragma unroll
        for (int c = 0; c < 16; ++c) {
            float4 xv = *(const float4*)&pool[P_XCW + w * NS + 4 * c];  // broadcast
            a0 = fmaf(arow[c].x, xv.x, a0);
            a1 = fmaf(arow[c].y, xv.y, a1);
            a2 = fmaf(arow[c].z, xv.z, a2);
            a3 = fmaf(arow[c].w, xv.w, a3);
        }
        const float xn = ((a0 + a1) + (a2 + a3)) + bbl * ur[s];
        pool[P_XCW + w * NS + l] = xn;    // next iter reads via broadcast
        Xl[l * ST + t] = xn;
    }
    __syncthreads();

    // phase2: stage C^T over the whole pool (stride 128)
#pragma unroll
    for (int rep = 0; rep < 8; ++rep) {
        const int ii = tid & 63;
        const int cg = (tid >> 6) + 4 * rep;   // 0..31
        float4 v;
        v.x = Cm[(4 * cg + 0) * NS + ii];
        v.y = Cm[(4 * cg + 1) * NS + ii];
        v.z = Cm[(4 * cg + 2) * NS + ii];
        v.w = Cm[(4 * cg + 3) * NS + ii];
        *(float4*)&pool[ii * CP + 4 * cg] = v;
    }
    __syncthreads();

    {
        const int tg = tid & 7, cq = tid >> 3;   // t0 = 8*tg, c0 = 4*cq
        float acc[4][8];
#pragma unroll
        for (int r = 0; r < 4; ++r)
#pragma unroll
            for (int c = 0; c < 8; ++c) acc[r][c] = 0.f;
#pragma unroll 4
        for (int ii = 0; ii < NS; ++ii) {
            float4 cv = *(const float4*)&pool[ii * CP + 4 * cq];
            float4 xa = *(const float4*)&Xl[ii * ST + 8 * tg + 0];
            float4 xb = *(const float4*)&Xl[ii * ST + 8 * tg + 4];
            float cr[4] = {cv.x, cv.y, cv.z, cv.w};
            float xv[8] = {xa.x, xa.y, xa.z, xa.w, xb.x, xb.y, xb.z, xb.w};
#pragma unroll
            for (int r = 0; r < 4; ++r)
#pragma unroll
                for (int c = 0; c < 8; ++c) acc[r][c] += cr[r] * xv[c];
        }
        const size_t obase = ((size_t)b * CH) * LSEQ + (size_t)m * SCH + 8 * tg;
#pragma unroll
        for (int r = 0; r < 4; ++r) {
            const int c = 4 * cq + r;
            const float dv = DS[c];
            float4 o1, o2;
            o1.x = acc[r][0] + dv * uS[8 * tg + 0];
            o1.y = acc[r][1] + dv * uS[8 * tg + 1];
            o1.z = acc[r][2] + dv * uS[8 * tg + 2];
            o1.w = acc[r][3] + dv * uS[8 * tg + 3];
            o2.x = acc[r][4] + dv * uS[8 * tg + 4];
            o2.y = acc[r][5] + dv * uS[8 * tg + 5];
            o2.z = acc[r][6] + dv * uS[8 * tg + 6];
            o2.w = acc[r][7] + dv * uS[8 * tg + 7];
            float* op = out + obase + (size_t)c * LSEQ;
            *(float4*)(op)     = o1;
            *(float4*)(op + 4) = o2;
        }
    }
}

extern "C" void kernel_launch(void* const* d_in, const int* in_sizes, int n_in,
                              void* d_out, int out_size, void* d_ws, size_t ws_size,
                              hipStream_t stream) {
    const float* u   = (const float*)d_in[0];
    const float* A   = (const float*)d_in[1];
    const float* Bv  = (const float*)d_in[2];
    const float* Cm  = (const float*)d_in[3];
    const float* Dv  = (const float*)d_in[4];
    const float* dtp = (const float*)d_in[5];
    float* ws  = (float*)d_ws;
    float* out = (float*)d_out;

    k_sb<<<NB, 1024, 0, stream>>>(u, A, Bv, dtp, ws, out);
    k_main2<<<dim3(MCH, NB), 256, 0, stream>>>(u, Cm, Dv, ws, out);
}

// Round 11
// 151.606 us; speedup vs baseline: 1.0066x; 1.0066x over previous
//
#include <hip/hip_runtime.h>

#define NS   64      // state dim
#define CH   128     // channels
#define LSEQ 4096    // sequence length
#define NB   16      // batch
#define SCH  64      // chunk size
#define MCH  64      // number of chunks (LSEQ/SCH)
#define ST   68      // padded LDS row stride (68*4 = 272B, 16B-aligned)
#define CP   128     // C^T pool stride (reads are uniform-row -> conflict-free)

// ws float offsets
#define WS_ABAR 0          // 64*64 A_bar row-major
#define WS_A16  4096       // 64*64 A_bar^16
#define WS_VS   8192       // 64*64 vs[j*64+i]
#define WS_BBAR 12288      // 64

// X0 stash in d_out: slot (b,m) later written only by k_main block (m,b).
#define X0_IDX(b, m) (((size_t)(b) * CH) * LSEQ + (size_t)(m) * SCH)

// k_main2 pool aliasing (floats): phase1 scratch + A16, then C^T (8192 f)
#define P_VSS  0
#define P_XCW  1024
#define P_XBS  1280
#define P_PLE  1536
#define P_PART 1792
#define P_A16  2048

#define FMA44(av, bv)                                                          \
    a0.x += av.x * bv.x; a0.y += av.x * bv.y; a0.z += av.x * bv.z; a0.w += av.x * bv.w; \
    a1.x += av.y * bv.x; a1.y += av.y * bv.y; a1.z += av.y * bv.z; a1.w += av.y * bv.w; \
    a2.x += av.z * bv.x; a2.y += av.z * bv.y; a2.z += av.z * bv.z; a2.w += av.z * bv.w; \
    a3.x += av.w * bv.x; a3.y += av.w * bv.y; a3.z += av.w * bv.z; a3.w += av.w * bv.w;

// NOTE (lower-triangularity): HiPPO A is lower-triangular, hence A_bar and all
// its powers are EXACTLY lower-triangular (the substitution produces exact 0.0f
// above the diagonal). In C = A*A, terms with k > i vanish, so k-loops truncate
// at the tile's last row +1. Upper tiles compute exact zeros and still write
// them -> no consumer change needed.

// 64x64 lower-tri matrix square on 256 threads (e = 0..255): (cm,cmt) -> (nm[,nmt]).
// cmt[k][i] = cm[i][k]. WT=false skips the transposed copy.
template<bool WT>
__device__ __forceinline__ void mm_square(const float* __restrict__ cm,
                                          const float* __restrict__ cmt,
                                          float* __restrict__ nm,
                                          float* __restrict__ nmt, int e) {
    const int l = e & 63;
    const int si0 = 16 * ((e >> 6) & 3) + 4 * (l >> 4);
    const int sj0 = 4 * (l & 15);
    const int kmax = si0 + 4;   // lower-tri: A[i][k]=0 for k>i (exact)
    float4 a0 = {0,0,0,0}, a1 = {0,0,0,0}, a2 = {0,0,0,0}, a3 = {0,0,0,0};
    for (int k = 0; k < kmax; k += 4) {
        float4 av0 = *(const float4*)&cmt[(k + 0) * ST + si0];
        float4 bv0 = *(const float4*)&cm [(k + 0) * ST + sj0];
        float4 av1 = *(const float4*)&cmt[(k + 1) * ST + si0];
        float4 bv1 = *(const float4*)&cm [(k + 1) * ST + sj0];
        float4 av2 = *(const float4*)&cmt[(k + 2) * ST + si0];
        float4 bv2 = *(const float4*)&cm [(k + 2) * ST + sj0];
        float4 av3 = *(const float4*)&cmt[(k + 3) * ST + si0];
        float4 bv3 = *(const float4*)&cm [(k + 3) * ST + sj0];
        FMA44(av0, bv0)
        FMA44(av1, bv1)
        FMA44(av2, bv2)
        FMA44(av3, bv3)
    }
    *(float4*)&nm[(si0 + 0) * ST + sj0] = a0;
    *(float4*)&nm[(si0 + 1) * ST + sj0] = a1;
    *(float4*)&nm[(si0 + 2) * ST + sj0] = a2;
    *(float4*)&nm[(si0 + 3) * ST + sj0] = a3;
    if (WT) {
        float4 t0 = {a0.x, a1.x, a2.x, a3.x};
        float4 t1 = {a0.y, a1.y, a2.y, a3.y};
        float4 t2 = {a0.z, a1.z, a2.z, a3.z};
        float4 t3 = {a0.w, a1.w, a2.w, a3.w};
        *(float4*)&nmt[(sj0 + 0) * ST + si0] = t0;
        *(float4*)&nmt[(sj0 + 1) * ST + si0] = t1;
        *(float4*)&nmt[(sj0 + 2) * ST + si0] = t2;
        *(float4*)&nmt[(sj0 + 3) * ST + si0] = t3;
    }
}

// 64x64 lower-tri square on ALL 1024 threads: 4-row x 1-col tile per thread.
// si0 is wave-uniform -> the A-operand float4 load is a broadcast (conflict-free,
// one LDS op per wave); per-wave FMA halves vs the 512-thread 4x2 tiling.
__device__ __forceinline__ void mm_sq41(const float* __restrict__ cm,
                                        const float* __restrict__ cmt,
                                        float* __restrict__ nm,
                                        float* __restrict__ nmt, int tid) {
    const int si0 = 4 * (tid >> 6);     // 16 i-quads, uniform per wave
    const int j   = tid & 63;
    const int kmax = si0 + 4;           // lower-tri truncation (exact)
    float a0 = 0.f, a1 = 0.f, a2 = 0.f, a3 = 0.f;
#pragma unroll 4
    for (int k = 0; k < kmax; ++k) {
        float4 av = *(const float4*)&cmt[k * ST + si0];   // broadcast
        float  bv = cm[k * ST + j];
        a0 = fmaf(av.x, bv, a0); a1 = fmaf(av.y, bv, a1);
        a2 = fmaf(av.z, bv, a2); a3 = fmaf(av.w, bv, a3);
    }
    nm[(si0 + 0) * ST + j] = a0;
    nm[(si0 + 1) * ST + j] = a1;
    nm[(si0 + 2) * ST + j] = a2;
    nm[(si0 + 3) * ST + j] = a3;
    float4 t = {a0, a1, a2, a3};
    *(float4*)&nmt[j * ST + si0] = t;
}

// vs-expansion, (i-quad, j) shape: VT[:, mexp+j] += cmt-power * VT[:, j].
// Caller guards thread range. iq in [0,16), j in [0,nj).
__device__ __forceinline__ void vs_expand1(const float* __restrict__ cmt,
                                           float* __restrict__ VT,
                                           int iq, int j, int mexp) {
    const int i0 = 4 * iq;
    float4 acc = {0,0,0,0};
#pragma unroll 8
    for (int k = 0; k < NS; ++k) {
        float4 av = *(const float4*)&cmt[k * ST + i0];
        float bk = VT[k * ST + j];
        acc.x += av.x * bk; acc.y += av.y * bk;
        acc.z += av.z * bk; acc.w += av.w * bk;
    }
    VT[(i0 + 0) * ST + mexp + j] = acc.x;
    VT[(i0 + 1) * ST + mexp + j] = acc.y;
    VT[(i0 + 2) * ST + mexp + j] = acc.z;
    VT[(i0 + 3) * ST + mexp + j] = acc.w;
}

// PQ step on 256 threads: outb[g] = A64*xle[4g+r0] + xle[4g+r0+1]
// Acol[k*ST+i] = A64[i][k].
__device__ __forceinline__ void pq_step(const float* __restrict__ Acol,
                                        const float* __restrict__ xle,
                                        float* __restrict__ outb, int r0, int e) {
    const int g = e >> 4, i0 = 4 * (e & 15);
    const float* bp = &xle[(4 * g + r0) * NS];
    float4 acc = *(const float4*)&xle[(4 * g + r0 + 1) * NS + i0];
#pragma unroll 8
    for (int k = 0; k < NS; ++k) {
        float4 av = *(const float4*)&Acol[k * ST + i0];
        float bk = bp[k];
        acc.x = fmaf(av.x, bk, acc.x); acc.y = fmaf(av.y, bk, acc.y);
        acc.z = fmaf(av.z, bk, acc.z); acc.w = fmaf(av.w, bk, acc.w);
    }
    *(float4*)&outb[g * ST + i0] = acc;
}

// Y step on 512 threads (float2 tiles): Y[g] = A128*P[g] + Q[g]
__device__ __forceinline__ void y_step512(const float* __restrict__ A128col,
                                          const float* __restrict__ P,
                                          const float* __restrict__ Q,
                                          float* __restrict__ Y, int e) {
    const int g = e >> 5, c0 = 2 * (e & 31);
    const float* bp = &P[g * ST];            // 32-lane broadcast
    float2 acc = *(const float2*)&Q[g * ST + c0];
#pragma unroll 8
    for (int k = 0; k < NS; ++k) {
        float2 av = *(const float2*)&A128col[k * ST + c0];
        float bk = bp[k];
        acc.x = fmaf(av.x, bk, acc.x); acc.y = fmaf(av.y, bk, acc.y);
    }
    *(float2*)&Y[g * ST + c0] = acc;
}

// Interior expansion on 256 threads: stash[4g+r] = A64*stash[4g+r-1] + xle[4g+r-1].
__device__ __forceinline__ void inner_step(const float* __restrict__ Acol,
                                           const float* __restrict__ xle,
                                           float* __restrict__ stash, int r, int e) {
    const int g = e >> 4, i0 = 4 * (e & 15);
    const int mp = 4 * g + r - 1;
    float4 acc = *(const float4*)&xle[mp * NS + i0];
    const float* xp = &stash[mp * ST];
#pragma unroll 8
    for (int k = 0; k < NS; ++k) {
        float4 av = *(const float4*)&Acol[k * ST + i0];
        float xk = xp[k];
        acc.x = fmaf(av.x, xk, acc.x); acc.y = fmaf(av.y, xk, acc.y);
        acc.z = fmaf(av.z, xk, acc.z); acc.w = fmaf(av.w, xk, acc.w);
    }
    *(float4*)&stash[(mp + 1) * ST + i0] = acc;
}

// Interior expansion on 512 threads (float2 tiles), r fixed.
__device__ __forceinline__ void inner512(const float* __restrict__ Acol,
                                         const float* __restrict__ xle,
                                         float* __restrict__ stash, int r, int e) {
    const int g = e >> 5, c0 = 2 * (e & 31);
    const int mp = 4 * g + r - 1;
    float2 acc = *(const float2*)&xle[mp * NS + c0];
    const float* xp = &stash[mp * ST];       // 32-lane broadcast
#pragma unroll 8
    for (int k = 0; k < NS; ++k) {
        float2 av = *(const float2*)&Acol[k * ST + c0];
        float xk = xp[k];
        acc.x = fmaf(av.x, xk, acc.x); acc.y = fmaf(av.y, xk, acc.y);
    }
    *(float2*)&stash[(mp + 1) * ST + c0] = acc;
}

// E1-upper on 256 threads: stash[4g+2] = A128*stash[4g] + P[g]
__device__ __forceinline__ void e1u_step(const float* __restrict__ A128col,
                                         const float* __restrict__ P,
                                         float* __restrict__ stash, int e) {
    const int g = e >> 4, i0 = 4 * (e & 15);
    const float* xp = &stash[(4 * g) * ST];
    float4 acc = *(const float4*)&P[g * ST + i0];
#pragma unroll 8
    for (int k = 0; k < NS; ++k) {
        float4 av = *(const float4*)&A128col[k * ST + i0];
        float xk = xp[k];
        acc.x = fmaf(av.x, xk, acc.x); acc.y = fmaf(av.y, xk, acc.y);
        acc.z = fmaf(av.z, xk, acc.z); acc.w = fmaf(av.w, xk, acc.w);
    }
    *(float4*)&stash[(4 * g + 2) * ST + i0] = acc;
}

// ---------------------------------------------------------------------------
// K1: setup + shortened boundary scan, 1024 threads.
// __launch_bounds__(1024, 4): 4 waves/EU minimum = exactly one 16-wave block
// per CU -> VGPR ceiling 128 (not 64). Round 10's regression was the compiler
// capping at 60 VGPRs and SPILLING the substitution's xr[64] to scratch
// (VGPR_Count 88->60, FETCH +47KB). This is the single change vs round 10.
// ---------------------------------------------------------------------------
__global__ __launch_bounds__(1024, 4) void k_sb(const float* __restrict__ u,
                                                const float* __restrict__ A,
                                                const float* __restrict__ Bv,
                                                const float* __restrict__ dtp,
                                                float* __restrict__ ws,
                                                float* __restrict__ out) {
    __shared__ __align__(16) float Mrow[NS * ST];        // power ping-pong (row)
    __shared__ __align__(16) float Mcol[(NS + 1) * ST];  // transposed; row 64 = B_bar
    __shared__ __align__(16) float Nrow[NS * ST];
    __shared__ __align__(16) float Ncol[NS * ST];
    __shared__ __align__(16) float VT[NS * ST];          // vs cols, then A^256 rows
    __shared__ __align__(16) float uT[NS * ST];          // uT, then X0 stash [m*ST+i]
    __shared__ __align__(16) float vsS[NS * NS];         // vs[j][i], then P/Q/Y bufs
    __shared__ __align__(16) float xleS[MCH * NS];       // xle[m][i]
    __shared__ __align__(16) float bcol[NS];
    __shared__ float rdiag[NS], xcS[NS];
    float* const stash = uT;              // X0 stash (uT dead after xle)
    float* const HbP = vsS;               // P buffer (vsS dead after xle)
    float* const HbQ = vsS + 16 * ST;     // Q buffer
    float* const HbY = vsS + 32 * ST;     // Y buffer (48*ST = 3264 <= 4096 ok)
    const int tid = threadIdx.x;
    const int b = blockIdx.x;
    const float dt = dtp[0];
    const float hdt = 0.5f * dt;

    // A-setup (no zero-init: every read location is written first)
    for (int o = tid; o < NS * NS; o += 1024) {
        int i = o >> 6, k = o & 63;
        float a = A[o];
        float d = (i == k) ? 1.0f : 0.0f;
        Nrow[i * ST + k] = d - hdt * a;   // T1
        Ncol[k * ST + i] = d + hdt * a;   // T2^T
    }
    if (tid < NS) {
        bcol[tid]  = dt * Bv[tid];
        rdiag[tid] = 1.0f / (1.0f - hdt * A[tid * NS + tid]);
    }
    __syncthreads();

    // stage u transposed early: uT[jj][m] = u[b][m*64 + 63-jj] (1 float4/thread)
    {
        const int jj = tid & 63;
        const int m0 = 4 * (tid >> 6);   // 0,4,...,60
        float4 v;
        v.x = u[b * LSEQ + (m0 + 0) * SCH + 63 - jj];
        v.y = u[b * LSEQ + (m0 + 1) * SCH + 63 - jj];
        v.z = u[b * LSEQ + (m0 + 2) * SCH + 63 - jj];
        v.w = u[b * LSEQ + (m0 + 3) * SCH + 63 - jj];
        *(float4*)&uT[jj * ST + m0] = v;
    }

    // forward substitution, column j in registers (lane j; tid==64 -> B_bar)
    if (tid <= NS) {
        float xr[NS];
        const float* t2b = (tid < NS) ? &Ncol[tid * ST] : bcol;
#pragma unroll
        for (int I = 0; I < 16; ++I) {
            const int i0 = 4 * I;
            float4 t2 = *(const float4*)&t2b[i0];
            float a0 = t2.x, a1 = t2.y, a2 = t2.z, a3 = t2.w;
#pragma unroll
            for (int k = 0; k < i0; k += 4) {
                float4 n0 = *(const float4*)&Nrow[(i0 + 0) * ST + k];
                float4 n1 = *(const float4*)&Nrow[(i0 + 1) * ST + k];
                float4 n2 = *(const float4*)&Nrow[(i0 + 2) * ST + k];
                float4 n3 = *(const float4*)&Nrow[(i0 + 3) * ST + k];
                a0 -= n0.x * xr[k] + n0.y * xr[k + 1] + n0.z * xr[k + 2] + n0.w * xr[k + 3];
                a1 -= n1.x * xr[k] + n1.y * xr[k + 1] + n1.z * xr[k + 2] + n1.w * xr[k + 3];
                a2 -= n2.x * xr[k] + n2.y * xr[k + 1] + n2.z * xr[k + 2] + n2.w * xr[k + 3];
                a3 -= n3.x * xr[k] + n3.y * xr[k + 1] + n3.z * xr[k + 2] + n3.w * xr[k + 3];
            }
            float4 rd  = *(const float4*)&rdiag[i0];
            float4 nb1 = *(const float4*)&Nrow[(i0 + 1) * ST + i0];
            float4 nb2 = *(const float4*)&Nrow[(i0 + 2) * ST + i0];
            float4 nb3 = *(const float4*)&Nrow[(i0 + 3) * ST + i0];
            float x0 = a0 * rd.x;
            float x1 = (a1 - nb1.x * x0) * rd.y;
            float x2 = (a2 - nb2.x * x0 - nb2.y * x1) * rd.z;
            float x3 = (a3 - nb3.x * x0 - nb3.y * x1 - nb3.z * x2) * rd.w;
            xr[i0 + 0] = x0; xr[i0 + 1] = x1; xr[i0 + 2] = x2; xr[i0 + 3] = x3;
        }
        float* xrow = &Mcol[tid * ST];
#pragma unroll
        for (int k = 0; k < NS; k += 4) {
            float4 v = {xr[k], xr[k + 1], xr[k + 2], xr[k + 3]};
            *(float4*)&xrow[k] = v;
        }
    }
    __syncthreads();

    // transpose Mcol -> Mrow; b0 stores ABAR, b1 stores BBAR; seed VT col 0
    if (tid < 256) {
        const int i0 = 4 * (tid >> 4), j0 = 4 * (tid & 15);
        float4 r0 = *(const float4*)&Mcol[(j0 + 0) * ST + i0];
        float4 r1 = *(const float4*)&Mcol[(j0 + 1) * ST + i0];
        float4 r2 = *(const float4*)&Mcol[(j0 + 2) * ST + i0];
        float4 r3 = *(const float4*)&Mcol[(j0 + 3) * ST + i0];
        float4 w0 = {r0.x, r1.x, r2.x, r3.x};
        float4 w1 = {r0.y, r1.y, r2.y, r3.y};
        float4 w2 = {r0.z, r1.z, r2.z, r3.z};
        float4 w3 = {r0.w, r1.w, r2.w, r3.w};
        *(float4*)&Mrow[(i0 + 0) * ST + j0] = w0;
        *(float4*)&Mrow[(i0 + 1) * ST + j0] = w1;
        *(float4*)&Mrow[(i0 + 2) * ST + j0] = w2;
        *(float4*)&Mrow[(i0 + 3) * ST + j0] = w3;
        if (b == 0) {
            *(float4*)&ws[WS_ABAR + (i0 + 0) * NS + j0] = w0;
            *(float4*)&ws[WS_ABAR + (i0 + 1) * NS + j0] = w1;
            *(float4*)&ws[WS_ABAR + (i0 + 2) * NS + j0] = w2;
            *(float4*)&ws[WS_ABAR + (i0 + 3) * NS + j0] = w3;
        }
    }
    if (b == 1 && tid < 16)
        *(float4*)&ws[WS_BBAR + 4 * tid] = *(const float4*)&Mcol[NS * ST + 4 * tid];
    if (tid < NS) VT[tid * ST + 0] = Mcol[NS * ST + tid];
    __syncthreads();

    // 6 levels of squaring with vs-expansion.
    //  s<=4: all 1024 threads square (4x1, broadcast A), inline expansion.
    //  s=5: 256-thread square || 256-thread expansion.
    //  s=6: 256-thread square || 512-thread expansion (1 col/thread).
    float *cm = Mrow, *cmt = Mcol, *nm = Nrow, *nmt = Ncol;
    for (int s = 1; s <= 6; ++s) {
        if (s <= 4) {
            mm_sq41(cm, cmt, nm, nmt, tid);
            const int mexp = 1 << (s - 1);   // 1,2,4,8 = nj
            if (tid < 16 * mexp) {
                vs_expand1(cmt, VT, tid & 15, tid >> 4, mexp);
            }
        } else if (tid < 256) {
            mm_square<true>(cm, cmt, nm, nmt, tid);
        } else {
            const int e = tid - 256;
            if (s == 5) {
                if (e < 256) vs_expand1(cmt, VT, e & 15, e >> 4, 16);
            } else {
                if (e < 512) vs_expand1(cmt, VT, e & 15, e >> 4, 32);
            }
        }
        __syncthreads();
        { float* t = cm; cm = nm; nm = t; t = cmt; cmt = nmt; nmt = t; }
        if (s == 4 && b == 2) {   // cm == A^16
            for (int o = tid; o < (NS * NS) / 4; o += 1024) {
                int r = o >> 4, c4 = (o & 15) * 4;
                *(float4*)&ws[WS_A16 + r * NS + c4] = *(const float4*)&cm[r * ST + c4];
            }
        }
    }
    // (Mrow, Mcol) = A^64 pair; (Nrow, Ncol) = A^32 (dead).

    // Phase A: tid<256: VT -> vsS transpose (+ b3 VS store).
    //          tid in [256,512): A^128 square (M-pair -> N-pair).
    if (tid < 256) {
        const int i0 = 4 * (tid >> 4), j0 = 4 * (tid & 15);
        float4 v0 = *(const float4*)&VT[(i0 + 0) * ST + j0];
        float4 v1 = *(const float4*)&VT[(i0 + 1) * ST + j0];
        float4 v2 = *(const float4*)&VT[(i0 + 2) * ST + j0];
        float4 v3 = *(const float4*)&VT[(i0 + 3) * ST + j0];
        float4 w0 = {v0.x, v1.x, v2.x, v3.x};
        float4 w1 = {v0.y, v1.y, v2.y, v3.y};
        float4 w2 = {v0.z, v1.z, v2.z, v3.z};
        float4 w3 = {v0.w, v1.w, v2.w, v3.w};
        *(float4*)&vsS[(j0 + 0) * NS + i0] = w0;
        *(float4*)&vsS[(j0 + 1) * NS + i0] = w1;
        *(float4*)&vsS[(j0 + 2) * NS + i0] = w2;
        *(float4*)&vsS[(j0 + 3) * NS + i0] = w3;
        if (b == 3) {
            *(float4*)&ws[WS_VS + (j0 + 0) * NS + i0] = w0;
            *(float4*)&ws[WS_VS + (j0 + 1) * NS + i0] = w1;
            *(float4*)&ws[WS_VS + (j0 + 2) * NS + i0] = w2;
            *(float4*)&ws[WS_VS + (j0 + 3) * NS + i0] = w3;
        }
    } else if (tid < 512) {
        mm_square<true>(Mrow, Mcol, Nrow, Ncol, tid - 256);   // A^128
    }
    __syncthreads();

    // Phase B: tid<256: xle[m][i] = sum_j vs[j][i] * uT[j][m].
    //          tid in [256,512): A^256 square, rows only -> VT (VT dead).
    if (tid < 256) {
        const int ig = tid & 15, mg = tid >> 4;
        float4 a0 = {0,0,0,0}, a1 = {0,0,0,0}, a2 = {0,0,0,0}, a3 = {0,0,0,0};
#pragma unroll 4
        for (int j = 0; j < NS; j += 2) {
            float4 am  = *(const float4*)&uT[j * ST + 4 * mg];
            float4 bi  = *(const float4*)&vsS[j * NS + 4 * ig];
            float4 am2 = *(const float4*)&uT[(j + 1) * ST + 4 * mg];
            float4 bi2 = *(const float4*)&vsS[(j + 1) * NS + 4 * ig];
            FMA44(am, bi)
            FMA44(am2, bi2)
        }
        *(float4*)&xleS[(4 * mg + 0) * NS + 4 * ig] = a0;
        *(float4*)&xleS[(4 * mg + 1) * NS + 4 * ig] = a1;
        *(float4*)&xleS[(4 * mg + 2) * NS + 4 * ig] = a2;
        *(float4*)&xleS[(4 * mg + 3) * NS + 4 * ig] = a3;
    } else if (tid < 512) {
        mm_square<false>(Nrow, Ncol, VT, VT, tid - 256);      // A^256 rows
    }
    __syncthreads();

    // Phase C1: P[g] = A64*xle_{4g} + xle_{4g+1}  (tid<256)
    //           Q[g] = A64*xle_{4g+2} + xle_{4g+3} (tid in [256,512))
    // tid<64 inits scan state (stash=uT is dead).
    if (tid < 256) pq_step(Mcol, xleS, HbP, 0, tid);
    else if (tid < 512) pq_step(Mcol, xleS, HbQ, 2, tid - 256);
    if (tid < 64) { xcS[tid] = 0.f; stash[tid] = 0.f; }   // Z_0 = X0_0 = 0
    __syncthreads();

    // Phase C2: Y[g] = A128*P[g] + Q[g] on 512 threads (float2 tiles).
    if (tid < 512) y_step512(Ncol, HbP, HbQ, HbY, tid);
    __syncthreads();

    // Phase D: 15-step serial scan  Z_{g+1} = A256 * Z_g + Y_g.
    // SINGLE WAVE: lane i holds row i of A^256 in 16 float4 regs; xc is read
    // from xcS via uniform (broadcast, conflict-free) float4 loads; Y vectors
    // preloaded into registers. No barriers in the loop.
    if (tid < 64) {
        const int i = tid;
        float4 arow[16];
#pragma unroll
        for (int c = 0; c < 16; ++c)
            arow[c] = *(const float4*)&VT[i * ST + 4 * c];
        float yv[15];
#pragma unroll
        for (int g = 0; g < 15; ++g) yv[g] = HbY[g * ST + i];
        for (int g = 0; g < 15; ++g) {
            float a0 = 0.f, a1 = 0.f, a2 = 0.f, a3 = 0.f;
#pragma unroll
            for (int c = 0; c < 16; ++c) {
                float4 xv = *(const float4*)&xcS[4 * c];
                a0 = fmaf(arow[c].x, xv.x, a0);
                a1 = fmaf(arow[c].y, xv.y, a1);
                a2 = fmaf(arow[c].z, xv.z, a2);
                a3 = fmaf(arow[c].w, xv.w, a3);
            }
            const float xn = ((a0 + a1) + (a2 + a3)) + yv[g];
            xcS[i] = xn;                       // next iter reads via broadcast
            stash[(4 * g + 4) * ST + i] = xn;  // X0_{4(g+1)} (fire-and-forget)
        }
    }
    __syncthreads();

    // Phase E1: stash[4g+1] = A64*stash[4g] + xle_{4g}      (tid<256)
    //           stash[4g+2] = A128*stash[4g] + P[g]         (tid in [256,512))
    if (tid < 256) inner_step(Mcol, xleS, stash, 1, tid);
    else if (tid < 512) e1u_step(Ncol, HbP, stash, tid - 256);
    __syncthreads();

    // Phase E2: stash[4g+3] = A64*stash[4g+2] + xle_{4g+2}  (512, float2)
    if (tid < 512) inner512(Mcol, xleS, stash, 3, tid);
    __syncthreads();

    // Phase F: bulk-store X0 (single drain; 1 float4/thread)
    {
        const int m = tid >> 4, t4 = (tid & 15) * 4;
        float4 o1 = *(const float4*)&stash[m * ST + t4];
        *(float4*)&out[X0_IDX(b, m) + t4] = o1;
    }
}

// ---------------------------------------------------------------------------
// K2: main. (round-9 kernel, unchanged — row-per-lane recurrence proven)
// ---------------------------------------------------------------------------
__global__ __launch_bounds__(256) void k_main2(const float* __restrict__ u,
                                               const float* __restrict__ Cm,
                                               const float* __restrict__ Dv,
                                               const float* __restrict__ ws,
                                               float* __restrict__ out) {
    __shared__ __align__(16) float Xl[NS * ST];     // A_bar staging, then X[i][t]
    __shared__ __align__(16) float pool[NS * CP];   // phase1 scratch+A16, then C^T
    __shared__ float uS[SCH], DS[CH], bbS[NS];
    const int m = blockIdx.x, b = blockIdx.y;
    const int tid = threadIdx.x;
    const int l = tid & 63, w = tid >> 6;

    for (int o = tid; o < (NS * NS) / 4; o += 256) {
        int r = o >> 4, c4 = (o & 15) * 4;
        *(float4*)&Xl[r * ST + c4]          = *(const float4*)&ws[WS_ABAR + r * NS + c4];
        *(float4*)&pool[P_A16 + r * NS + c4] = *(const float4*)&ws[WS_A16 + r * NS + c4];
    }
    for (int o = tid; o < 16 * NS; o += 256) pool[P_VSS + o] = ws[WS_VS + o];
    if (tid < NS) {
        uS[tid]  = u[b * LSEQ + m * SCH + tid];
        bbS[tid] = ws[WS_BBAR + tid];
        pool[P_XBS + tid] = out[X0_IDX(b, m) + tid];
    }
    if (tid < CH) DS[tid] = Dv[tid];
    __syncthreads();

    // Row-per-lane A_bar: lane l holds row l (16 float4 = 64 VGPR).
    float4 arow[16];
#pragma unroll
    for (int c = 0; c < 16; ++c)
        arow[c] = *(const float4*)&Xl[l * ST + 4 * c];
    const float bbl = bbS[l];
    float ur[16];
#pragma unroll
    for (int s = 0; s < 16; ++s) ur[s] = uS[16 * w + s];
    float4 a16r[4];
#pragma unroll
    for (int kq = 0; kq < 4; ++kq)
        a16r[kq] = *(const float4*)&pool[P_A16 + l * NS + 16 * w + 4 * kq];

    {
        float s = 0.f;
#pragma unroll
        for (int j = 0; j < 16; ++j) s += pool[P_VSS + j * NS + l] * uS[16 * w + 15 - j];
        pool[P_PLE + w * NS + l] = s;
    }
    __syncthreads();

    for (int p = 1; p < 4; ++p) {
        float4 x0q = *(const float4*)&pool[P_XBS + (p - 1) * NS + 16 * w + 0];
        float4 x1q = *(const float4*)&pool[P_XBS + (p - 1) * NS + 16 * w + 4];
        float4 x2q = *(const float4*)&pool[P_XBS + (p - 1) * NS + 16 * w + 8];
        float4 x3q = *(const float4*)&pool[P_XBS + (p - 1) * NS + 16 * w + 12];
        float s = a16r[0].x * x0q.x + a16r[0].y * x0q.y + a16r[0].z * x0q.z + a16r[0].w * x0q.w
                + a16r[1].x * x1q.x + a16r[1].y * x1q.y + a16r[1].z * x1q.z + a16r[1].w * x1q.w
                + a16r[2].x * x2q.x + a16r[2].y * x2q.y + a16r[2].z * x2q.z + a16r[2].w * x2q.w
                + a16r[3].x * x3q.x + a16r[3].y * x3q.y + a16r[3].z * x3q.z + a16r[3].w * x3q.w;
        pool[P_PART + w * NS + l] = s;
        __syncthreads();
        if (w == 0) {
            float xn = pool[P_PART + l] + pool[P_PART + NS + l] + pool[P_PART + 2 * NS + l]
                     + pool[P_PART + 3 * NS + l] + pool[P_PLE + (p - 1) * NS + l];
            pool[P_XBS + p * NS + l] = xn;
        }
        __syncthreads();
    }

    // Within-paragraph recurrence, row-per-lane (wave-private LDS slice).
    pool[P_XCW + w * NS + l] = pool[P_XBS + w * NS + l];
    for (int s = 0; s < 16; ++s) {
        const int t = 16 * w + s;
        float a0 = 0.f, a1 = 0.f, a2 = 0.f, a3 = 0.f;
#pragma unroll
        for (int c = 0; c < 16; ++c) {
            float4 xv = *(const float4*)&pool[P_XCW + w * NS + 4 * c];  // broadcast
            a0 = fmaf(arow[c].x, xv.x, a0);
            a1 = fmaf(arow[c].y, xv.y, a1);
            a2 = fmaf(arow[c].z, xv.z, a2);
            a3 = fmaf(arow[c].w, xv.w, a3);
        }
        const float xn = ((a0 + a1) + (a2 + a3)) + bbl * ur[s];
        pool[P_XCW + w * NS + l] = xn;    // next iter reads via broadcast
        Xl[l * ST + t] = xn;
    }
    __syncthreads();

    // phase2: stage C^T over the whole pool (stride 128)
#pragma unroll
    for (int rep = 0; rep < 8; ++rep) {
        const int ii = tid & 63;
        const int cg = (tid >> 6) + 4 * rep;   // 0..31
        float4 v;
        v.x = Cm[(4 * cg + 0) * NS + ii];
        v.y = Cm[(4 * cg + 1) * NS + ii];
        v.z = Cm[(4 * cg + 2) * NS + ii];
        v.w = Cm[(4 * cg + 3) * NS + ii];
        *(float4*)&pool[ii * CP + 4 * cg] = v;
    }
    __syncthreads();

    {
        const int tg = tid & 7, cq = tid >> 3;   // t0 = 8*tg, c0 = 4*cq
        float acc[4][8];
#pragma unroll
        for (int r = 0; r < 4; ++r)
#pragma unroll
            for (int c = 0; c < 8; ++c) acc[r][c] = 0.f;
#pragma unroll 4
        for (int ii = 0; ii < NS; ++ii) {
            float4 cv = *(const float4*)&pool[ii * CP + 4 * cq];
            float4 xa = *(const float4*)&Xl[ii * ST + 8 * tg + 0];
            float4 xb = *(const float4*)&Xl[ii * ST + 8 * tg + 4];
            float cr[4] = {cv.x, cv.y, cv.z, cv.w};
            float xv[8] = {xa.x, xa.y, xa.z, xa.w, xb.x, xb.y, xb.z, xb.w};
#pragma unroll
            for (int r = 0; r < 4; ++r)
#pragma unroll
                for (int c = 0; c < 8; ++c) acc[r][c] += cr[r] * xv[c];
        }
        const size_t obase = ((size_t)b * CH) * LSEQ + (size_t)m * SCH + 8 * tg;
#pragma unroll
        for (int r = 0; r < 4; ++r) {
            const int c = 4 * cq + r;
            const float dv = DS[c];
            float4 o1, o2;
            o1.x = acc[r][0] + dv * uS[8 * tg + 0];
            o1.y = acc[r][1] + dv * uS[8 * tg + 1];
            o1.z = acc[r][2] + dv * uS[8 * tg + 2];
            o1.w = acc[r][3] + dv * uS[8 * tg + 3];
            o2.x = acc[r][4] + dv * uS[8 * tg + 4];
            o2.y = acc[r][5] + dv * uS[8 * tg + 5];
            o2.z = acc[r][6] + dv * uS[8 * tg + 6];
            o2.w = acc[r][7] + dv * uS[8 * tg + 7];
            float* op = out + obase + (size_t)c * LSEQ;
            *(float4*)(op)     = o1;
            *(float4*)(op + 4) = o2;
        }
    }
}

extern "C" void kernel_launch(void* const* d_in, const int* in_sizes, int n_in,
                              void* d_out, int out_size, void* d_ws, size_t ws_size,
                              hipStream_t stream) {
    const float* u   = (const float*)d_in[0];
    const float* A   = (const float*)d_in[1];
    const float* Bv  = (const float*)d_in[2];
    const float* Cm  = (const float*)d_in[3];
    const float* Dv  = (const float*)d_in[4];
    const float* dtp = (const float*)d_in[5];
    float* ws  = (float*)d_ws;
    float* out = (float*)d_out;

    k_sb<<<NB, 1024, 0, stream>>>(u, A, Bv, dtp, ws, out);
    k_main2<<<dim3(MCH, NB), 256, 0, stream>>>(u, Cm, Dv, ws, out);
}

// Round 12
// 149.899 us; speedup vs baseline: 1.0181x; 1.0114x over previous
//
#include <hip/hip_runtime.h>

#define NS   64      // state dim
#define CH   128     // channels
#define LSEQ 4096    // sequence length
#define NB   16      // batch
#define SCH  64      // chunk size
#define MCH  64      // number of chunks (LSEQ/SCH)
#define ST   68      // padded LDS row stride (68*4 = 272B, 16B-aligned)
#define CP   128     // C^T pool stride (reads are uniform-row -> conflict-free)

// ws float offsets
#define WS_ABAR 0          // 64*64 A_bar row-major
#define WS_A16  4096       // 64*64 A_bar^16
#define WS_VS   8192       // 64*64 vs[j*64+i]
#define WS_BBAR 12288      // 64

// X0 stash in d_out: slot (b,m) later written only by k_main block (m,b).
#define X0_IDX(b, m) (((size_t)(b) * CH) * LSEQ + (size_t)(m) * SCH)

// k_main2 pool aliasing (floats): phase1 scratch + A16, then C^T (8192 f)
#define P_VSS  0
#define P_XCW  1024
#define P_XBS  1280
#define P_PLE  1536
#define P_PART 1792
#define P_A16  2048

#define FMA44(av, bv)                                                          \
    a0.x += av.x * bv.x; a0.y += av.x * bv.y; a0.z += av.x * bv.z; a0.w += av.x * bv.w; \
    a1.x += av.y * bv.x; a1.y += av.y * bv.y; a1.z += av.y * bv.z; a1.w += av.y * bv.w; \
    a2.x += av.z * bv.x; a2.y += av.z * bv.y; a2.z += av.z * bv.z; a2.w += av.z * bv.w; \
    a3.x += av.w * bv.x; a3.y += av.w * bv.y; a3.z += av.w * bv.z; a3.w += av.w * bv.w;

// NOTE (lower-triangularity): HiPPO A is lower-triangular, hence A_bar and all
// its powers are EXACTLY lower-triangular (the substitution produces exact 0.0f
// above the diagonal). In C = A*A, terms with k > i vanish, so k-loops truncate
// at the tile's last row +1. Upper tiles compute exact zeros and still write
// them -> no consumer change needed.

// 64x64 lower-tri matrix square on 256 threads (e = 0..255): (cm,cmt) -> (nm[,nmt]).
// cmt[k][i] = cm[i][k]. WT=false skips the transposed copy.
template<bool WT>
__device__ __forceinline__ void mm_square(const float* __restrict__ cm,
                                          const float* __restrict__ cmt,
                                          float* __restrict__ nm,
                                          float* __restrict__ nmt, int e) {
    const int l = e & 63;
    const int si0 = 16 * ((e >> 6) & 3) + 4 * (l >> 4);
    const int sj0 = 4 * (l & 15);
    const int kmax = si0 + 4;   // lower-tri: A[i][k]=0 for k>i (exact)
    float4 a0 = {0,0,0,0}, a1 = {0,0,0,0}, a2 = {0,0,0,0}, a3 = {0,0,0,0};
    for (int k = 0; k < kmax; k += 4) {
        float4 av0 = *(const float4*)&cmt[(k + 0) * ST + si0];
        float4 bv0 = *(const float4*)&cm [(k + 0) * ST + sj0];
        float4 av1 = *(const float4*)&cmt[(k + 1) * ST + si0];
        float4 bv1 = *(const float4*)&cm [(k + 1) * ST + sj0];
        float4 av2 = *(const float4*)&cmt[(k + 2) * ST + si0];
        float4 bv2 = *(const float4*)&cm [(k + 2) * ST + sj0];
        float4 av3 = *(const float4*)&cmt[(k + 3) * ST + si0];
        float4 bv3 = *(const float4*)&cm [(k + 3) * ST + sj0];
        FMA44(av0, bv0)
        FMA44(av1, bv1)
        FMA44(av2, bv2)
        FMA44(av3, bv3)
    }
    *(float4*)&nm[(si0 + 0) * ST + sj0] = a0;
    *(float4*)&nm[(si0 + 1) * ST + sj0] = a1;
    *(float4*)&nm[(si0 + 2) * ST + sj0] = a2;
    *(float4*)&nm[(si0 + 3) * ST + sj0] = a3;
    if (WT) {
        float4 t0 = {a0.x, a1.x, a2.x, a3.x};
        float4 t1 = {a0.y, a1.y, a2.y, a3.y};
        float4 t2 = {a0.z, a1.z, a2.z, a3.z};
        float4 t3 = {a0.w, a1.w, a2.w, a3.w};
        *(float4*)&nmt[(sj0 + 0) * ST + si0] = t0;
        *(float4*)&nmt[(sj0 + 1) * ST + si0] = t1;
        *(float4*)&nmt[(sj0 + 2) * ST + si0] = t2;
        *(float4*)&nmt[(sj0 + 3) * ST + si0] = t3;
    }
}

// 64x64 lower-tri square on ALL 512 threads: 4-row x 2-col tile per thread.
__device__ __forceinline__ void mm_sq42(const float* __restrict__ cm,
                                        const float* __restrict__ cmt,
                                        float* __restrict__ nm,
                                        float* __restrict__ nmt, int tid) {
    const int si0 = 4 * (tid >> 5);     // 16 i-quads
    const int sj0 = 2 * (tid & 31);     // 32 j-pairs
    const int kmax = si0 + 4;           // lower-tri truncation (exact)
    float2 a0 = {0,0}, a1 = {0,0}, a2 = {0,0}, a3 = {0,0};
#pragma unroll 4
    for (int k = 0; k < kmax; ++k) {
        float4 av = *(const float4*)&cmt[k * ST + si0];
        float2 bv = *(const float2*)&cm [k * ST + sj0];
        a0.x += av.x * bv.x; a0.y += av.x * bv.y;
        a1.x += av.y * bv.x; a1.y += av.y * bv.y;
        a2.x += av.z * bv.x; a2.y += av.z * bv.y;
        a3.x += av.w * bv.x; a3.y += av.w * bv.y;
    }
    *(float2*)&nm[(si0 + 0) * ST + sj0] = a0;
    *(float2*)&nm[(si0 + 1) * ST + sj0] = a1;
    *(float2*)&nm[(si0 + 2) * ST + sj0] = a2;
    *(float2*)&nm[(si0 + 3) * ST + sj0] = a3;
    float4 t0 = {a0.x, a1.x, a2.x, a3.x};
    float4 t1 = {a0.y, a1.y, a2.y, a3.y};
    *(float4*)&nmt[(sj0 + 0) * ST + si0] = t0;
    *(float4*)&nmt[(sj0 + 1) * ST + si0] = t1;
}

// vs-expansion, (i-quad, j) shape: VT[:, mexp+j] += cmt-power * VT[:, j].
// Caller guards thread range. iq in [0,16), j in [0,nj).
__device__ __forceinline__ void vs_expand1(const float* __restrict__ cmt,
                                           float* __restrict__ VT,
                                           int iq, int j, int mexp) {
    const int i0 = 4 * iq;
    float4 acc = {0,0,0,0};
#pragma unroll 8
    for (int k = 0; k < NS; ++k) {
        float4 av = *(const float4*)&cmt[k * ST + i0];
        float bk = VT[k * ST + j];
        acc.x += av.x * bk; acc.y += av.y * bk;
        acc.z += av.z * bk; acc.w += av.w * bk;
    }
    VT[(i0 + 0) * ST + mexp + j] = acc.x;
    VT[(i0 + 1) * ST + mexp + j] = acc.y;
    VT[(i0 + 2) * ST + mexp + j] = acc.z;
    VT[(i0 + 3) * ST + mexp + j] = acc.w;
}

// PQ step on 256 threads: outb[g] = A64*xle[4g+r0] + xle[4g+r0+1]
// Acol[k*ST+i] = A64[i][k].
__device__ __forceinline__ void pq_step(const float* __restrict__ Acol,
                                        const float* __restrict__ xle,
                                        float* __restrict__ outb, int r0, int e) {
    const int g = e >> 4, i0 = 4 * (e & 15);
    const float* bp = &xle[(4 * g + r0) * NS];
    float4 acc = *(const float4*)&xle[(4 * g + r0 + 1) * NS + i0];
#pragma unroll 8
    for (int k = 0; k < NS; ++k) {
        float4 av = *(const float4*)&Acol[k * ST + i0];
        float bk = bp[k];
        acc.x = fmaf(av.x, bk, acc.x); acc.y = fmaf(av.y, bk, acc.y);
        acc.z = fmaf(av.z, bk, acc.z); acc.w = fmaf(av.w, bk, acc.w);
    }
    *(float4*)&outb[g * ST + i0] = acc;
}

// Y step on ALL 512 threads (float2 tiles): Y[g] = A128*P[g] + Q[g]
__device__ __forceinline__ void y_step512(const float* __restrict__ A128col,
                                          const float* __restrict__ P,
                                          const float* __restrict__ Q,
                                          float* __restrict__ Y, int e) {
    const int g = e >> 5, c0 = 2 * (e & 31);
    const float* bp = &P[g * ST];            // 32-lane broadcast
    float2 acc = *(const float2*)&Q[g * ST + c0];
#pragma unroll 8
    for (int k = 0; k < NS; ++k) {
        float2 av = *(const float2*)&A128col[k * ST + c0];
        float bk = bp[k];
        acc.x = fmaf(av.x, bk, acc.x); acc.y = fmaf(av.y, bk, acc.y);
    }
    *(float2*)&Y[g * ST + c0] = acc;
}

// Interior expansion on 256 threads: stash[4g+r] = A64*stash[4g+r-1] + xle[4g+r-1].
__device__ __forceinline__ void inner_step(const float* __restrict__ Acol,
                                           const float* __restrict__ xle,
                                           float* __restrict__ stash, int r, int e) {
    const int g = e >> 4, i0 = 4 * (e & 15);
    const int mp = 4 * g + r - 1;
    float4 acc = *(const float4*)&xle[mp * NS + i0];
    const float* xp = &stash[mp * ST];
#pragma unroll 8
    for (int k = 0; k < NS; ++k) {
        float4 av = *(const float4*)&Acol[k * ST + i0];
        float xk = xp[k];
        acc.x = fmaf(av.x, xk, acc.x); acc.y = fmaf(av.y, xk, acc.y);
        acc.z = fmaf(av.z, xk, acc.z); acc.w = fmaf(av.w, xk, acc.w);
    }
    *(float4*)&stash[(mp + 1) * ST + i0] = acc;
}

// Interior expansion on ALL 512 threads (float2 tiles), r fixed.
__device__ __forceinline__ void inner512(const float* __restrict__ Acol,
                                         const float* __restrict__ xle,
                                         float* __restrict__ stash, int r, int e) {
    const int g = e >> 5, c0 = 2 * (e & 31);
    const int mp = 4 * g + r - 1;
    float2 acc = *(const float2*)&xle[mp * NS + c0];
    const float* xp = &stash[mp * ST];       // 32-lane broadcast
#pragma unroll 8
    for (int k = 0; k < NS; ++k) {
        float2 av = *(const float2*)&Acol[k * ST + c0];
        float xk = xp[k];
        acc.x = fmaf(av.x, xk, acc.x); acc.y = fmaf(av.y, xk, acc.y);
    }
    *(float2*)&stash[(mp + 1) * ST + c0] = acc;
}

// E1-upper on 256 threads: stash[4g+2] = A128*stash[4g] + P[g]
__device__ __forceinline__ void e1u_step(const float* __restrict__ A128col,
                                         const float* __restrict__ P,
                                         float* __restrict__ stash, int e) {
    const int g = e >> 4, i0 = 4 * (e & 15);
    const float* xp = &stash[(4 * g) * ST];
    float4 acc = *(const float4*)&P[g * ST + i0];
#pragma unroll 8
    for (int k = 0; k < NS; ++k) {
        float4 av = *(const float4*)&A128col[k * ST + i0];
        float xk = xp[k];
        acc.x = fmaf(av.x, xk, acc.x); acc.y = fmaf(av.y, xk, acc.y);
        acc.z = fmaf(av.z, xk, acc.z); acc.w = fmaf(av.w, xk, acc.w);
    }
    *(float4*)&stash[(4 * g + 2) * ST + i0] = acc;
}

// ---------------------------------------------------------------------------
// K1: setup + shortened boundary scan, 512 threads. (round-9 proven kernel;
// 1024-thread variants regress: compiler caps VGPR at 60 and spills xr[64])
// ---------------------------------------------------------------------------
__global__ __launch_bounds__(512) void k_sb(const float* __restrict__ u,
                                            const float* __restrict__ A,
                                            const float* __restrict__ Bv,
                                            const float* __restrict__ dtp,
                                            float* __restrict__ ws,
                                            float* __restrict__ out) {
    __shared__ __align__(16) float Mrow[NS * ST];        // power ping-pong (row)
    __shared__ __align__(16) float Mcol[(NS + 1) * ST];  // transposed; row 64 = B_bar
    __shared__ __align__(16) float Nrow[NS * ST];
    __shared__ __align__(16) float Ncol[NS * ST];
    __shared__ __align__(16) float VT[NS * ST];          // vs cols, then A^256 rows
    __shared__ __align__(16) float uT[NS * ST];          // uT, then X0 stash [m*ST+i]
    __shared__ __align__(16) float vsS[NS * NS];         // vs[j][i], then P/Q/Y bufs
    __shared__ __align__(16) float xleS[MCH * NS];       // xle[m][i]
    __shared__ __align__(16) float bcol[NS];
    __shared__ float rdiag[NS], xcS[NS];
    float* const stash = uT;              // X0 stash (uT dead after xle)
    float* const HbP = vsS;               // P buffer (vsS dead after xle)
    float* const HbQ = vsS + 16 * ST;     // Q buffer
    float* const HbY = vsS + 32 * ST;     // Y buffer (48*ST = 3264 <= 4096 ok)
    const int tid = threadIdx.x;
    const int b = blockIdx.x;
    const float dt = dtp[0];
    const float hdt = 0.5f * dt;

    // A-setup (no zero-init: every read location is written first)
    for (int o = tid; o < NS * NS; o += 512) {
        int i = o >> 6, k = o & 63;
        float a = A[o];
        float d = (i == k) ? 1.0f : 0.0f;
        Nrow[i * ST + k] = d - hdt * a;   // T1
        Ncol[k * ST + i] = d + hdt * a;   // T2^T
    }
    if (tid < NS) {
        bcol[tid]  = dt * Bv[tid];
        rdiag[tid] = 1.0f / (1.0f - hdt * A[tid * NS + tid]);
    }
    __syncthreads();

    // stage u transposed early: uT[jj][m] = u[b][m*64 + 63-jj]
    {
        const int jj = tid & 63;
#pragma unroll
        for (int rep = 0; rep < 2; ++rep) {
            const int m0 = 4 * (tid >> 6) + 32 * rep;
            float4 v;
            v.x = u[b * LSEQ + (m0 + 0) * SCH + 63 - jj];
            v.y = u[b * LSEQ + (m0 + 1) * SCH + 63 - jj];
            v.z = u[b * LSEQ + (m0 + 2) * SCH + 63 - jj];
            v.w = u[b * LSEQ + (m0 + 3) * SCH + 63 - jj];
            *(float4*)&uT[jj * ST + m0] = v;
        }
    }

    // forward substitution, column j in registers (lane j; tid==64 -> B_bar)
    if (tid <= NS) {
        float xr[NS];
        const float* t2b = (tid < NS) ? &Ncol[tid * ST] : bcol;
#pragma unroll
        for (int I = 0; I < 16; ++I) {
            const int i0 = 4 * I;
            float4 t2 = *(const float4*)&t2b[i0];
            float a0 = t2.x, a1 = t2.y, a2 = t2.z, a3 = t2.w;
#pragma unroll
            for (int k = 0; k < i0; k += 4) {
                float4 n0 = *(const float4*)&Nrow[(i0 + 0) * ST + k];
                float4 n1 = *(const float4*)&Nrow[(i0 + 1) * ST + k];
                float4 n2 = *(const float4*)&Nrow[(i0 + 2) * ST + k];
                float4 n3 = *(const float4*)&Nrow[(i0 + 3) * ST + k];
                a0 -= n0.x * xr[k] + n0.y * xr[k + 1] + n0.z * xr[k + 2] + n0.w * xr[k + 3];
                a1 -= n1.x * xr[k] + n1.y * xr[k + 1] + n1.z * xr[k + 2] + n1.w * xr[k + 3];
                a2 -= n2.x * xr[k] + n2.y * xr[k + 1] + n2.z * xr[k + 2] + n2.w * xr[k + 3];
                a3 -= n3.x * xr[k] + n3.y * xr[k + 1] + n3.z * xr[k + 2] + n3.w * xr[k + 3];
            }
            float4 rd  = *(const float4*)&rdiag[i0];
            float4 nb1 = *(const float4*)&Nrow[(i0 + 1) * ST + i0];
            float4 nb2 = *(const float4*)&Nrow[(i0 + 2) * ST + i0];
            float4 nb3 = *(const float4*)&Nrow[(i0 + 3) * ST + i0];
            float x0 = a0 * rd.x;
            float x1 = (a1 - nb1.x * x0) * rd.y;
            float x2 = (a2 - nb2.x * x0 - nb2.y * x1) * rd.z;
            float x3 = (a3 - nb3.x * x0 - nb3.y * x1 - nb3.z * x2) * rd.w;
            xr[i0 + 0] = x0; xr[i0 + 1] = x1; xr[i0 + 2] = x2; xr[i0 + 3] = x3;
        }
        float* xrow = &Mcol[tid * ST];
#pragma unroll
        for (int k = 0; k < NS; k += 4) {
            float4 v = {xr[k], xr[k + 1], xr[k + 2], xr[k + 3]};
            *(float4*)&xrow[k] = v;
        }
    }
    __syncthreads();

    // transpose Mcol -> Mrow; b0 stores ABAR, b1 stores BBAR; seed VT col 0
    if (tid < 256) {
        const int i0 = 4 * (tid >> 4), j0 = 4 * (tid & 15);
        float4 r0 = *(const float4*)&Mcol[(j0 + 0) * ST + i0];
        float4 r1 = *(const float4*)&Mcol[(j0 + 1) * ST + i0];
        float4 r2 = *(const float4*)&Mcol[(j0 + 2) * ST + i0];
        float4 r3 = *(const float4*)&Mcol[(j0 + 3) * ST + i0];
        float4 w0 = {r0.x, r1.x, r2.x, r3.x};
        float4 w1 = {r0.y, r1.y, r2.y, r3.y};
        float4 w2 = {r0.z, r1.z, r2.z, r3.z};
        float4 w3 = {r0.w, r1.w, r2.w, r3.w};
        *(float4*)&Mrow[(i0 + 0) * ST + j0] = w0;
        *(float4*)&Mrow[(i0 + 1) * ST + j0] = w1;
        *(float4*)&Mrow[(i0 + 2) * ST + j0] = w2;
        *(float4*)&Mrow[(i0 + 3) * ST + j0] = w3;
        if (b == 0) {
            *(float4*)&ws[WS_ABAR + (i0 + 0) * NS + j0] = w0;
            *(float4*)&ws[WS_ABAR + (i0 + 1) * NS + j0] = w1;
            *(float4*)&ws[WS_ABAR + (i0 + 2) * NS + j0] = w2;
            *(float4*)&ws[WS_ABAR + (i0 + 3) * NS + j0] = w3;
        }
    }
    if (b == 1 && tid < 16)
        *(float4*)&ws[WS_BBAR + 4 * tid] = *(const float4*)&Mcol[NS * ST + 4 * tid];
    if (tid < NS) VT[tid * ST + 0] = Mcol[NS * ST + tid];
    __syncthreads();

    // 6 levels of squaring with vs-expansion.
    float *cm = Mrow, *cmt = Mcol, *nm = Nrow, *nmt = Ncol;
    for (int s = 1; s <= 6; ++s) {
        if (s <= 4) {
            mm_sq42(cm, cmt, nm, nmt, tid);
            const int mexp = 1 << (s - 1);   // 1,2,4,8 = nj
            if (tid < 16 * mexp) {
                vs_expand1(cmt, VT, tid & 15, tid >> 4, mexp);
            }
        } else if (tid < 256) {
            mm_square<true>(cm, cmt, nm, nmt, tid);
        } else {
            const int e = tid - 256;
            const int iq = e & 15;
            if (s == 5) {
                vs_expand1(cmt, VT, iq, e >> 4, 16);
            } else {
                // s == 6: 2 columns per thread (j0, j0+1)
                const int j0 = 2 * (e >> 4);
                const int i0 = 4 * iq;
                float4 c0 = {0,0,0,0}, c1 = {0,0,0,0};
#pragma unroll 8
                for (int k = 0; k < NS; ++k) {
                    float4 av = *(const float4*)&cmt[k * ST + i0];
                    float2 bv = *(const float2*)&VT[k * ST + j0];
                    c0.x += av.x * bv.x; c0.y += av.y * bv.x;
                    c0.z += av.z * bv.x; c0.w += av.w * bv.x;
                    c1.x += av.x * bv.y; c1.y += av.y * bv.y;
                    c1.z += av.z * bv.y; c1.w += av.w * bv.y;
                }
                float2 w0 = {c0.x, c1.x}, w1 = {c0.y, c1.y};
                float2 w2 = {c0.z, c1.z}, w3 = {c0.w, c1.w};
                *(float2*)&VT[(i0 + 0) * ST + 32 + j0] = w0;
                *(float2*)&VT[(i0 + 1) * ST + 32 + j0] = w1;
                *(float2*)&VT[(i0 + 2) * ST + 32 + j0] = w2;
                *(float2*)&VT[(i0 + 3) * ST + 32 + j0] = w3;
            }
        }
        __syncthreads();
        { float* t = cm; cm = nm; nm = t; t = cmt; cmt = nmt; nmt = t; }
        if (s == 4 && b == 2) {   // cm == A^16
            for (int o = tid; o < (NS * NS) / 4; o += 512) {
                int r = o >> 4, c4 = (o & 15) * 4;
                *(float4*)&ws[WS_A16 + r * NS + c4] = *(const float4*)&cm[r * ST + c4];
            }
        }
    }
    // (Mrow, Mcol) = A^64 pair; (Nrow, Ncol) = A^32 (dead).

    // Phase A: waves 0-3: VT -> vsS transpose (+ b3 VS store).
    //          waves 4-7: A^128 square (M-pair -> N-pair, both layouts kept).
    if (tid < 256) {
        const int i0 = 4 * (tid >> 4), j0 = 4 * (tid & 15);
        float4 v0 = *(const float4*)&VT[(i0 + 0) * ST + j0];
        float4 v1 = *(const float4*)&VT[(i0 + 1) * ST + j0];
        float4 v2 = *(const float4*)&VT[(i0 + 2) * ST + j0];
        float4 v3 = *(const float4*)&VT[(i0 + 3) * ST + j0];
        float4 w0 = {v0.x, v1.x, v2.x, v3.x};
        float4 w1 = {v0.y, v1.y, v2.y, v3.y};
        float4 w2 = {v0.z, v1.z, v2.z, v3.z};
        float4 w3 = {v0.w, v1.w, v2.w, v3.w};
        *(float4*)&vsS[(j0 + 0) * NS + i0] = w0;
        *(float4*)&vsS[(j0 + 1) * NS + i0] = w1;
        *(float4*)&vsS[(j0 + 2) * NS + i0] = w2;
        *(float4*)&vsS[(j0 + 3) * NS + i0] = w3;
        if (b == 3) {
            *(float4*)&ws[WS_VS + (j0 + 0) * NS + i0] = w0;
            *(float4*)&ws[WS_VS + (j0 + 1) * NS + i0] = w1;
            *(float4*)&ws[WS_VS + (j0 + 2) * NS + i0] = w2;
            *(float4*)&ws[WS_VS + (j0 + 3) * NS + i0] = w3;
        }
    } else {
        mm_square<true>(Mrow, Mcol, Nrow, Ncol, tid - 256);   // A^128
    }
    __syncthreads();

    // Phase B: waves 0-3: xle[m][i] = sum_j vs[j][i] * uT[j][m].
    //          waves 4-7: A^256 square, rows only -> VT (VT dead).
    if (tid < 256) {
        const int ig = tid & 15, mg = tid >> 4;
        float4 a0 = {0,0,0,0}, a1 = {0,0,0,0}, a2 = {0,0,0,0}, a3 = {0,0,0,0};
#pragma unroll 4
        for (int j = 0; j < NS; j += 2) {
            float4 am  = *(const float4*)&uT[j * ST + 4 * mg];
            float4 bi  = *(const float4*)&vsS[j * NS + 4 * ig];
            float4 am2 = *(const float4*)&uT[(j + 1) * ST + 4 * mg];
            float4 bi2 = *(const float4*)&vsS[(j + 1) * NS + 4 * ig];
            FMA44(am, bi)
            FMA44(am2, bi2)
        }
        *(float4*)&xleS[(4 * mg + 0) * NS + 4 * ig] = a0;
        *(float4*)&xleS[(4 * mg + 1) * NS + 4 * ig] = a1;
        *(float4*)&xleS[(4 * mg + 2) * NS + 4 * ig] = a2;
        *(float4*)&xleS[(4 * mg + 3) * NS + 4 * ig] = a3;
    } else {
        mm_square<false>(Nrow, Ncol, VT, VT, tid - 256);      // A^256 rows
    }
    __syncthreads();

    // Phase C1: P[g] = A64*xle_{4g} + xle_{4g+1}  (waves 0-3)
    //           Q[g] = A64*xle_{4g+2} + xle_{4g+3} (waves 4-7)
    // tid<64 inits scan state (stash=uT is dead).
    if (tid < 256) pq_step(Mcol, xleS, HbP, 0, tid);
    else           pq_step(Mcol, xleS, HbQ, 2, tid - 256);
    if (tid < 64) { xcS[tid] = 0.f; stash[tid] = 0.f; }   // Z_0 = X0_0 = 0
    __syncthreads();

    // Phase C2: Y[g] = A128*P[g] + Q[g] on all 512 threads (float2 tiles).
    y_step512(Ncol, HbP, HbQ, HbY, tid);
    __syncthreads();

    // Phase D: 15-step serial scan  Z_{g+1} = A256 * Z_g + Y_g.
    // SINGLE WAVE: lane i holds row i of A^256 in 16 float4 regs; xc is read
    // from xcS via uniform (broadcast, conflict-free) float4 loads; Y vectors
    // preloaded into registers. No barriers in the loop.
    if (tid < 64) {
        const int i = tid;
        float4 arow[16];
#pragma unroll
        for (int c = 0; c < 16; ++c)
            arow[c] = *(const float4*)&VT[i * ST + 4 * c];
        float yv[15];
#pragma unroll
        for (int g = 0; g < 15; ++g) yv[g] = HbY[g * ST + i];
        for (int g = 0; g < 15; ++g) {
            float a0 = 0.f, a1 = 0.f, a2 = 0.f, a3 = 0.f;
#pragma unroll
            for (int c = 0; c < 16; ++c) {
                float4 xv = *(const float4*)&xcS[4 * c];
                a0 = fmaf(arow[c].x, xv.x, a0);
                a1 = fmaf(arow[c].y, xv.y, a1);
                a2 = fmaf(arow[c].z, xv.z, a2);
                a3 = fmaf(arow[c].w, xv.w, a3);
            }
            const float xn = ((a0 + a1) + (a2 + a3)) + yv[g];
            xcS[i] = xn;                       // next iter reads via broadcast
            stash[(4 * g + 4) * ST + i] = xn;  // X0_{4(g+1)} (fire-and-forget)
        }
    }
    __syncthreads();

    // Phase E1: stash[4g+1] = A64*stash[4g] + xle_{4g}      (waves 0-3)
    //           stash[4g+2] = A128*stash[4g] + P[g]         (waves 4-7)
    if (tid < 256) inner_step(Mcol, xleS, stash, 1, tid);
    else           e1u_step(Ncol, HbP, stash, tid - 256);
    __syncthreads();

    // Phase E2: stash[4g+3] = A64*stash[4g+2] + xle_{4g+2}  (all 512, float2)
    inner512(Mcol, xleS, stash, 3, tid);
    __syncthreads();

    // Phase F: bulk-store X0 (single drain at kernel end)
    {
        const int m = tid >> 3, t8 = (tid & 7) * 8;
        float4 o1 = *(const float4*)&stash[m * ST + t8];
        float4 o2 = *(const float4*)&stash[m * ST + t8 + 4];
        *(float4*)&out[X0_IDX(b, m) + t8]     = o1;
        *(float4*)&out[X0_IDX(b, m) + t8 + 4] = o2;
    }
}

// ---------------------------------------------------------------------------
// K2: main. (round-9 kernel — row-per-lane recurrence proven)
// ---------------------------------------------------------------------------
__global__ __launch_bounds__(256) void k_main2(const float* __restrict__ u,
                                               const float* __restrict__ Cm,
                                               const float* __restrict__ Dv,
                                               const float* __restrict__ ws,
                                               float* __restrict__ out) {
    __shared__ __align__(16) float Xl[NS * ST];     // A_bar staging, then X[i][t]
    __shared__ __align__(16) float pool[NS * CP];   // phase1 scratch+A16, then C^T
    __shared__ float uS[SCH], DS[CH], bbS[NS];
    const int m = blockIdx.x, b = blockIdx.y;
    const int tid = threadIdx.x;
    const int l = tid & 63, w = tid >> 6;

    for (int o = tid; o < (NS * NS) / 4; o += 256) {
        int r = o >> 4, c4 = (o & 15) * 4;
        *(float4*)&Xl[r * ST + c4]          = *(const float4*)&ws[WS_ABAR + r * NS + c4];
        *(float4*)&pool[P_A16 + r * NS + c4] = *(const float4*)&ws[WS_A16 + r * NS + c4];
    }
    for (int o = tid; o < 16 * NS; o += 256) pool[P_VSS + o] = ws[WS_VS + o];
    if (tid < NS) {
        uS[tid]  = u[b * LSEQ + m * SCH + tid];
        bbS[tid] = ws[WS_BBAR + tid];
        pool[P_XBS + tid] = out[X0_IDX(b, m) + tid];
    }
    if (tid < CH) DS[tid] = Dv[tid];
    __syncthreads();

    // Row-per-lane A_bar: lane l holds row l (16 float4 = 64 VGPR).
    float4 arow[16];
#pragma unroll
    for (int c = 0; c < 16; ++c)
        arow[c] = *(const float4*)&Xl[l * ST + 4 * c];
    const float bbl = bbS[l];
    float ur[16];
#pragma unroll
    for (int s = 0; s < 16; ++s) ur[s] = uS[16 * w + s];
    float4 a16r[4];
#pragma unroll
    for (int kq = 0; kq < 4; ++kq)
        a16r[kq] = *(const float4*)&pool[P_A16 + l * NS + 16 * w + 4 * kq];

    {
        float s = 0.f;
#pragma unroll
        for (int j = 0; j < 16; ++j) s += pool[P_VSS + j * NS + l] * uS[16 * w + 15 - j];
        pool[P_PLE + w * NS + l] = s;
    }
    __syncthreads();

    for (int p = 1; p < 4; ++p) {
        float4 x0q = *(const float4*)&pool[P_XBS + (p - 1) * NS + 16 * w + 0];
        float4 x1q = *(const float4*)&pool[P_XBS + (p - 1) * NS + 16 * w + 4];
        float4 x2q = *(const float4*)&pool[P_XBS + (p - 1) * NS + 16 * w + 8];
        float4 x3q = *(const float4*)&pool[P_XBS + (p - 1) * NS + 16 * w + 12];
        float s = a16r[0].x * x0q.x + a16r[0].y * x0q.y + a16r[0].z * x0q.z + a16r[0].w * x0q.w
                + a16r[1].x * x1q.x + a16r[1].y * x1q.y + a16r[1].z * x1q.z + a16r[1].w * x1q.w
                + a16r[2].x * x2q.x + a16r[2].y * x2q.y + a16r[2].z * x2q.z + a16r[2].w * x2q.w
                + a16r[3].x * x3q.x + a16r[3].y * x3q.y + a16r[3].z * x3q.z + a16r[3].w * x3q.w;
        pool[P_PART + w * NS + l] = s;
        __syncthreads();
        if (w == 0) {
            float xn = pool[P_PART + l] + pool[P_PART + NS + l] + pool[P_PART + 2 * NS + l]
                     + pool[P_PART + 3 * NS + l] + pool[P_PLE + (p - 1) * NS + l];
            pool[P_XBS + p * NS + l] = xn;
        }
        __syncthreads();
    }

    // Within-paragraph recurrence, row-per-lane (wave-private LDS slice).
    pool[P_XCW + w * NS + l] = pool[P_XBS + w * NS + l];
    for (int s = 0; s < 16; ++s) {
        const int t = 16 * w + s;
        float a0 = 0.f, a1 = 0.f, a2 = 0.f, a3 = 0.f;
#pragma unroll
        for (int c = 0; c < 16; ++c) {
            float4 xv = *(const float4*)&pool[P_XCW + w * NS + 4 * c];  // broadcast
            a0 = fmaf(arow[c].x, xv.x, a0);
            a1 = fmaf(arow[c].y, xv.y, a1);
            a2 = fmaf(arow[c].z, xv.z, a2);
            a3 = fmaf(arow[c].w, xv.w, a3);
        }
        const float xn = ((a0 + a1) + (a2 + a3)) + bbl * ur[s];
        pool[P_XCW + w * NS + l] = xn;    // next iter reads via broadcast
        Xl[l * ST + t] = xn;
    }
    __syncthreads();

    // phase2: stage C^T over the whole pool (stride 128)
#pragma unroll
    for (int rep = 0; rep < 8; ++rep) {
        const int ii = tid & 63;
        const int cg = (tid >> 6) + 4 * rep;   // 0..31
        float4 v;
        v.x = Cm[(4 * cg + 0) * NS + ii];
        v.y = Cm[(4 * cg + 1) * NS + ii];
        v.z = Cm[(4 * cg + 2) * NS + ii];
        v.w = Cm[(4 * cg + 3) * NS + ii];
        *(float4*)&pool[ii * CP + 4 * cg] = v;
    }
    __syncthreads();

    {
        const int tg = tid & 7, cq = tid >> 3;   // t0 = 8*tg, c0 = 4*cq
        float acc[4][8];
#pragma unroll
        for (int r = 0; r < 4; ++r)
#pragma unroll
            for (int c = 0; c < 8; ++c) acc[r][c] = 0.f;
#pragma unroll 4
        for (int ii = 0; ii < NS; ++ii) {
            float4 cv = *(const float4*)&pool[ii * CP + 4 * cq];
            float4 xa = *(const float4*)&Xl[ii * ST + 8 * tg + 0];
            float4 xb = *(const float4*)&Xl[ii * ST + 8 * tg + 4];
            float cr[4] = {cv.x, cv.y, cv.z, cv.w};
            float xv[8] = {xa.x, xa.y, xa.z, xa.w, xb.x, xb.y, xb.z, xb.w};
#pragma unroll
            for (int r = 0; r < 4; ++r)
#pragma unroll
                for (int c = 0; c < 8; ++c) acc[r][c] += cr[r] * xv[c];
        }
        const size_t obase = ((size_t)b * CH) * LSEQ + (size_t)m * SCH + 8 * tg;
#pragma unroll
        for (int r = 0; r < 4; ++r) {
            const int c = 4 * cq + r;
            const float dv = DS[c];
            float4 o1, o2;
            o1.x = acc[r][0] + dv * uS[8 * tg + 0];
            o1.y = acc[r][1] + dv * uS[8 * tg + 1];
            o1.z = acc[r][2] + dv * uS[8 * tg + 2];
            o1.w = acc[r][3] + dv * uS[8 * tg + 3];
            o2.x = acc[r][4] + dv * uS[8 * tg + 4];
            o2.y = acc[r][5] + dv * uS[8 * tg + 5];
            o2.z = acc[r][6] + dv * uS[8 * tg + 6];
            o2.w = acc[r][7] + dv * uS[8 * tg + 7];
            float* op = out + obase + (size_t)c * LSEQ;
            *(float4*)(op)     = o1;
            *(float4*)(op + 4) = o2;
        }
    }
}

extern "C" void kernel_launch(void* const* d_in, const int* in_sizes, int n_in,
                              void* d_out, int out_size, void* d_ws, size_t ws_size,
                              hipStream_t stream) {
    const float* u   = (const float*)d_in[0];
    const float* A   = (const float*)d_in[1];
    const float* Bv  = (const float*)d_in[2];
    const float* Cm  = (const float*)d_in[3];
    const float* Dv  = (const float*)d_in[4];
    const float* dtp = (const float*)d_in[5];
    float* ws  = (float*)d_ws;
    float* out = (float*)d_out;

    k_sb<<<NB, 512, 0, stream>>>(u, A, Bv, dtp, ws, out);
    k_main2<<<dim3(MCH, NB), 256, 0, stream>>>(u, Cm, Dv, ws, out);
}

// Round 13
// 145.248 us; speedup vs baseline: 1.0507x; 1.0320x over previous
//
#include <hip/hip_runtime.h>

#define NS   64      // state dim
#define CH   128     // channels
#define LSEQ 4096    // sequence length
#define NB   16      // batch
#define SCH  64      // chunk size
#define MCH  64      // number of chunks (LSEQ/SCH)
#define ST   68      // padded LDS row stride (68*4 = 272B, 16B-aligned)
#define CP   128     // C^T pool stride (reads are uniform-row -> conflict-free)

// ws float offsets
#define WS_ABAR 0          // 64*64 A_bar row-major
#define WS_A16  4096       // 64*64 A_bar^16
#define WS_VS   8192       // 64*64 vs[j*64+i]
#define WS_BBAR 12288      // 64

// X0 stash in d_out: slot (b,m) read then overwritten only by the k_main2
// block owning chunk pair (m>>1, b).
#define X0_IDX(b, m) (((size_t)(b) * CH) * LSEQ + (size_t)(m) * SCH)

// k_main2 pool aliasing (floats): phase1 scratch + A16, then C^T (8192 f)
#define P_VSS  0
#define P_XCW  1024
#define P_XBS  1280
#define P_PLE  1536
#define P_PART 1792
#define P_A16  2048

#define FMA44(av, bv)                                                          \
    a0.x += av.x * bv.x; a0.y += av.x * bv.y; a0.z += av.x * bv.z; a0.w += av.x * bv.w; \
    a1.x += av.y * bv.x; a1.y += av.y * bv.y; a1.z += av.y * bv.z; a1.w += av.y * bv.w; \
    a2.x += av.z * bv.x; a2.y += av.z * bv.y; a2.z += av.z * bv.z; a2.w += av.z * bv.w; \
    a3.x += av.w * bv.x; a3.y += av.w * bv.y; a3.z += av.w * bv.z; a3.w += av.w * bv.w;

// NOTE (lower-triangularity): HiPPO A is lower-triangular, hence A_bar and all
// its powers are EXACTLY lower-triangular (the substitution produces exact 0.0f
// above the diagonal). In C = A*A, terms with k > i vanish, so k-loops truncate
// at the tile's last row +1. Upper tiles compute exact zeros and still write
// them -> no consumer change needed.

// 64x64 lower-tri matrix square on 256 threads (e = 0..255): (cm,cmt) -> (nm[,nmt]).
// cmt[k][i] = cm[i][k]. WT=false skips the transposed copy.
template<bool WT>
__device__ __forceinline__ void mm_square(const float* __restrict__ cm,
                                          const float* __restrict__ cmt,
                                          float* __restrict__ nm,
                                          float* __restrict__ nmt, int e) {
    const int l = e & 63;
    const int si0 = 16 * ((e >> 6) & 3) + 4 * (l >> 4);
    const int sj0 = 4 * (l & 15);
    const int kmax = si0 + 4;   // lower-tri: A[i][k]=0 for k>i (exact)
    float4 a0 = {0,0,0,0}, a1 = {0,0,0,0}, a2 = {0,0,0,0}, a3 = {0,0,0,0};
    for (int k = 0; k < kmax; k += 4) {
        float4 av0 = *(const float4*)&cmt[(k + 0) * ST + si0];
        float4 bv0 = *(const float4*)&cm [(k + 0) * ST + sj0];
        float4 av1 = *(const float4*)&cmt[(k + 1) * ST + si0];
        float4 bv1 = *(const float4*)&cm [(k + 1) * ST + sj0];
        float4 av2 = *(const float4*)&cmt[(k + 2) * ST + si0];
        float4 bv2 = *(const float4*)&cm [(k + 2) * ST + sj0];
        float4 av3 = *(const float4*)&cmt[(k + 3) * ST + si0];
        float4 bv3 = *(const float4*)&cm [(k + 3) * ST + sj0];
        FMA44(av0, bv0)
        FMA44(av1, bv1)
        FMA44(av2, bv2)
        FMA44(av3, bv3)
    }
    *(float4*)&nm[(si0 + 0) * ST + sj0] = a0;
    *(float4*)&nm[(si0 + 1) * ST + sj0] = a1;
    *(float4*)&nm[(si0 + 2) * ST + sj0] = a2;
    *(float4*)&nm[(si0 + 3) * ST + sj0] = a3;
    if (WT) {
        float4 t0 = {a0.x, a1.x, a2.x, a3.x};
        float4 t1 = {a0.y, a1.y, a2.y, a3.y};
        float4 t2 = {a0.z, a1.z, a2.z, a3.z};
        float4 t3 = {a0.w, a1.w, a2.w, a3.w};
        *(float4*)&nmt[(sj0 + 0) * ST + si0] = t0;
        *(float4*)&nmt[(sj0 + 1) * ST + si0] = t1;
        *(float4*)&nmt[(sj0 + 2) * ST + si0] = t2;
        *(float4*)&nmt[(sj0 + 3) * ST + si0] = t3;
    }
}

// 64x64 lower-tri square on ALL 512 threads: 4-row x 2-col tile per thread.
__device__ __forceinline__ void mm_sq42(const float* __restrict__ cm,
                                        const float* __restrict__ cmt,
                                        float* __restrict__ nm,
                                        float* __restrict__ nmt, int tid) {
    const int si0 = 4 * (tid >> 5);     // 16 i-quads
    const int sj0 = 2 * (tid & 31);     // 32 j-pairs
    const int kmax = si0 + 4;           // lower-tri truncation (exact)
    float2 a0 = {0,0}, a1 = {0,0}, a2 = {0,0}, a3 = {0,0};
#pragma unroll 4
    for (int k = 0; k < kmax; ++k) {
        float4 av = *(const float4*)&cmt[k * ST + si0];
        float2 bv = *(const float2*)&cm [k * ST + sj0];
        a0.x += av.x * bv.x; a0.y += av.x * bv.y;
        a1.x += av.y * bv.x; a1.y += av.y * bv.y;
        a2.x += av.z * bv.x; a2.y += av.z * bv.y;
        a3.x += av.w * bv.x; a3.y += av.w * bv.y;
    }
    *(float2*)&nm[(si0 + 0) * ST + sj0] = a0;
    *(float2*)&nm[(si0 + 1) * ST + sj0] = a1;
    *(float2*)&nm[(si0 + 2) * ST + sj0] = a2;
    *(float2*)&nm[(si0 + 3) * ST + sj0] = a3;
    float4 t0 = {a0.x, a1.x, a2.x, a3.x};
    float4 t1 = {a0.y, a1.y, a2.y, a3.y};
    *(float4*)&nmt[(sj0 + 0) * ST + si0] = t0;
    *(float4*)&nmt[(sj0 + 1) * ST + si0] = t1;
}

// vs-expansion, (i-quad, j) shape: VT[:, mexp+j] += cmt-power * VT[:, j].
// Caller guards thread range. iq in [0,16), j in [0,nj).
__device__ __forceinline__ void vs_expand1(const float* __restrict__ cmt,
                                           float* __restrict__ VT,
                                           int iq, int j, int mexp) {
    const int i0 = 4 * iq;
    float4 acc = {0,0,0,0};
#pragma unroll 8
    for (int k = 0; k < NS; ++k) {
        float4 av = *(const float4*)&cmt[k * ST + i0];
        float bk = VT[k * ST + j];
        acc.x += av.x * bk; acc.y += av.y * bk;
        acc.z += av.z * bk; acc.w += av.w * bk;
    }
    VT[(i0 + 0) * ST + mexp + j] = acc.x;
    VT[(i0 + 1) * ST + mexp + j] = acc.y;
    VT[(i0 + 2) * ST + mexp + j] = acc.z;
    VT[(i0 + 3) * ST + mexp + j] = acc.w;
}

// PQ step on 256 threads: outb[g] = A64*xle[4g+r0] + xle[4g+r0+1]
// Acol[k*ST+i] = A64[i][k].
__device__ __forceinline__ void pq_step(const float* __restrict__ Acol,
                                        const float* __restrict__ xle,
                                        float* __restrict__ outb, int r0, int e) {
    const int g = e >> 4, i0 = 4 * (e & 15);
    const float* bp = &xle[(4 * g + r0) * NS];
    float4 acc = *(const float4*)&xle[(4 * g + r0 + 1) * NS + i0];
#pragma unroll 8
    for (int k = 0; k < NS; ++k) {
        float4 av = *(const float4*)&Acol[k * ST + i0];
        float bk = bp[k];
        acc.x = fmaf(av.x, bk, acc.x); acc.y = fmaf(av.y, bk, acc.y);
        acc.z = fmaf(av.z, bk, acc.z); acc.w = fmaf(av.w, bk, acc.w);
    }
    *(float4*)&outb[g * ST + i0] = acc;
}

// Y step on ALL 512 threads (float2 tiles): Y[g] = A128*P[g] + Q[g]
__device__ __forceinline__ void y_step512(const float* __restrict__ A128col,
                                          const float* __restrict__ P,
                                          const float* __restrict__ Q,
                                          float* __restrict__ Y, int e) {
    const int g = e >> 5, c0 = 2 * (e & 31);
    const float* bp = &P[g * ST];            // 32-lane broadcast
    float2 acc = *(const float2*)&Q[g * ST + c0];
#pragma unroll 8
    for (int k = 0; k < NS; ++k) {
        float2 av = *(const float2*)&A128col[k * ST + c0];
        float bk = bp[k];
        acc.x = fmaf(av.x, bk, acc.x); acc.y = fmaf(av.y, bk, acc.y);
    }
    *(float2*)&Y[g * ST + c0] = acc;
}

// Interior expansion on 256 threads: stash[4g+r] = A64*stash[4g+r-1] + xle[4g+r-1].
__device__ __forceinline__ void inner_step(const float* __restrict__ Acol,
                                           const float* __restrict__ xle,
                                           float* __restrict__ stash, int r, int e) {
    const int g = e >> 4, i0 = 4 * (e & 15);
    const int mp = 4 * g + r - 1;
    float4 acc = *(const float4*)&xle[mp * NS + i0];
    const float* xp = &stash[mp * ST];
#pragma unroll 8
    for (int k = 0; k < NS; ++k) {
        float4 av = *(const float4*)&Acol[k * ST + i0];
        float xk = xp[k];
        acc.x = fmaf(av.x, xk, acc.x); acc.y = fmaf(av.y, xk, acc.y);
        acc.z = fmaf(av.z, xk, acc.z); acc.w = fmaf(av.w, xk, acc.w);
    }
    *(float4*)&stash[(mp + 1) * ST + i0] = acc;
}

// Interior expansion on ALL 512 threads (float2 tiles), r fixed.
__device__ __forceinline__ void inner512(const float* __restrict__ Acol,
                                         const float* __restrict__ xle,
                                         float* __restrict__ stash, int r, int e) {
    const int g = e >> 5, c0 = 2 * (e & 31);
    const int mp = 4 * g + r - 1;
    float2 acc = *(const float2*)&xle[mp * NS + c0];
    const float* xp = &stash[mp * ST];       // 32-lane broadcast
#pragma unroll 8
    for (int k = 0; k < NS; ++k) {
        float2 av = *(const float2*)&Acol[k * ST + c0];
        float xk = xp[k];
        acc.x = fmaf(av.x, xk, acc.x); acc.y = fmaf(av.y, xk, acc.y);
    }
    *(float2*)&stash[(mp + 1) * ST + c0] = acc;
}

// E1-upper on 256 threads: stash[4g+2] = A128*stash[4g] + P[g]
__device__ __forceinline__ void e1u_step(const float* __restrict__ A128col,
                                         const float* __restrict__ P,
                                         float* __restrict__ stash, int e) {
    const int g = e >> 4, i0 = 4 * (e & 15);
    const float* xp = &stash[(4 * g) * ST];
    float4 acc = *(const float4*)&P[g * ST + i0];
#pragma unroll 8
    for (int k = 0; k < NS; ++k) {
        float4 av = *(const float4*)&A128col[k * ST + i0];
        float xk = xp[k];
        acc.x = fmaf(av.x, xk, acc.x); acc.y = fmaf(av.y, xk, acc.y);
        acc.z = fmaf(av.z, xk, acc.z); acc.w = fmaf(av.w, xk, acc.w);
    }
    *(float4*)&stash[(4 * g + 2) * ST + i0] = acc;
}

// ---------------------------------------------------------------------------
// K1: setup + shortened boundary scan, 512 threads. (round-9/12 proven kernel)
// ---------------------------------------------------------------------------
__global__ __launch_bounds__(512) void k_sb(const float* __restrict__ u,
                                            const float* __restrict__ A,
                                            const float* __restrict__ Bv,
                                            const float* __restrict__ dtp,
                                            float* __restrict__ ws,
                                            float* __restrict__ out) {
    __shared__ __align__(16) float Mrow[NS * ST];        // power ping-pong (row)
    __shared__ __align__(16) float Mcol[(NS + 1) * ST];  // transposed; row 64 = B_bar
    __shared__ __align__(16) float Nrow[NS * ST];
    __shared__ __align__(16) float Ncol[NS * ST];
    __shared__ __align__(16) float VT[NS * ST];          // vs cols, then A^256 rows
    __shared__ __align__(16) float uT[NS * ST];          // uT, then X0 stash [m*ST+i]
    __shared__ __align__(16) float vsS[NS * NS];         // vs[j][i], then P/Q/Y bufs
    __shared__ __align__(16) float xleS[MCH * NS];       // xle[m][i]
    __shared__ __align__(16) float bcol[NS];
    __shared__ float rdiag[NS], xcS[NS];
    float* const stash = uT;              // X0 stash (uT dead after xle)
    float* const HbP = vsS;               // P buffer (vsS dead after xle)
    float* const HbQ = vsS + 16 * ST;     // Q buffer
    float* const HbY = vsS + 32 * ST;     // Y buffer (48*ST = 3264 <= 4096 ok)
    const int tid = threadIdx.x;
    const int b = blockIdx.x;
    const float dt = dtp[0];
    const float hdt = 0.5f * dt;

    // A-setup (no zero-init: every read location is written first)
    for (int o = tid; o < NS * NS; o += 512) {
        int i = o >> 6, k = o & 63;
        float a = A[o];
        float d = (i == k) ? 1.0f : 0.0f;
        Nrow[i * ST + k] = d - hdt * a;   // T1
        Ncol[k * ST + i] = d + hdt * a;   // T2^T
    }
    if (tid < NS) {
        bcol[tid]  = dt * Bv[tid];
        rdiag[tid] = 1.0f / (1.0f - hdt * A[tid * NS + tid]);
    }
    __syncthreads();

    // stage u transposed early: uT[jj][m] = u[b][m*64 + 63-jj]
    {
        const int jj = tid & 63;
#pragma unroll
        for (int rep = 0; rep < 2; ++rep) {
            const int m0 = 4 * (tid >> 6) + 32 * rep;
            float4 v;
            v.x = u[b * LSEQ + (m0 + 0) * SCH + 63 - jj];
            v.y = u[b * LSEQ + (m0 + 1) * SCH + 63 - jj];
            v.z = u[b * LSEQ + (m0 + 2) * SCH + 63 - jj];
            v.w = u[b * LSEQ + (m0 + 3) * SCH + 63 - jj];
            *(float4*)&uT[jj * ST + m0] = v;
        }
    }

    // forward substitution, column j in registers (lane j; tid==64 -> B_bar)
    if (tid <= NS) {
        float xr[NS];
        const float* t2b = (tid < NS) ? &Ncol[tid * ST] : bcol;
#pragma unroll
        for (int I = 0; I < 16; ++I) {
            const int i0 = 4 * I;
            float4 t2 = *(const float4*)&t2b[i0];
            float a0 = t2.x, a1 = t2.y, a2 = t2.z, a3 = t2.w;
#pragma unroll
            for (int k = 0; k < i0; k += 4) {
                float4 n0 = *(const float4*)&Nrow[(i0 + 0) * ST + k];
                float4 n1 = *(const float4*)&Nrow[(i0 + 1) * ST + k];
                float4 n2 = *(const float4*)&Nrow[(i0 + 2) * ST + k];
                float4 n3 = *(const float4*)&Nrow[(i0 + 3) * ST + k];
                a0 -= n0.x * xr[k] + n0.y * xr[k + 1] + n0.z * xr[k + 2] + n0.w * xr[k + 3];
                a1 -= n1.x * xr[k] + n1.y * xr[k + 1] + n1.z * xr[k + 2] + n1.w * xr[k + 3];
                a2 -= n2.x * xr[k] + n2.y * xr[k + 1] + n2.z * xr[k + 2] + n2.w * xr[k + 3];
                a3 -= n3.x * xr[k] + n3.y * xr[k + 1] + n3.z * xr[k + 2] + n3.w * xr[k + 3];
            }
            float4 rd  = *(const float4*)&rdiag[i0];
            float4 nb1 = *(const float4*)&Nrow[(i0 + 1) * ST + i0];
            float4 nb2 = *(const float4*)&Nrow[(i0 + 2) * ST + i0];
            float4 nb3 = *(const float4*)&Nrow[(i0 + 3) * ST + i0];
            float x0 = a0 * rd.x;
            float x1 = (a1 - nb1.x * x0) * rd.y;
            float x2 = (a2 - nb2.x * x0 - nb2.y * x1) * rd.z;
            float x3 = (a3 - nb3.x * x0 - nb3.y * x1 - nb3.z * x2) * rd.w;
            xr[i0 + 0] = x0; xr[i0 + 1] = x1; xr[i0 + 2] = x2; xr[i0 + 3] = x3;
        }
        float* xrow = &Mcol[tid * ST];
#pragma unroll
        for (int k = 0; k < NS; k += 4) {
            float4 v = {xr[k], xr[k + 1], xr[k + 2], xr[k + 3]};
            *(float4*)&xrow[k] = v;
        }
    }
    __syncthreads();

    // transpose Mcol -> Mrow; b0 stores ABAR, b1 stores BBAR; seed VT col 0
    if (tid < 256) {
        const int i0 = 4 * (tid >> 4), j0 = 4 * (tid & 15);
        float4 r0 = *(const float4*)&Mcol[(j0 + 0) * ST + i0];
        float4 r1 = *(const float4*)&Mcol[(j0 + 1) * ST + i0];
        float4 r2 = *(const float4*)&Mcol[(j0 + 2) * ST + i0];
        float4 r3 = *(const float4*)&Mcol[(j0 + 3) * ST + i0];
        float4 w0 = {r0.x, r1.x, r2.x, r3.x};
        float4 w1 = {r0.y, r1.y, r2.y, r3.y};
        float4 w2 = {r0.z, r1.z, r2.z, r3.z};
        float4 w3 = {r0.w, r1.w, r2.w, r3.w};
        *(float4*)&Mrow[(i0 + 0) * ST + j0] = w0;
        *(float4*)&Mrow[(i0 + 1) * ST + j0] = w1;
        *(float4*)&Mrow[(i0 + 2) * ST + j0] = w2;
        *(float4*)&Mrow[(i0 + 3) * ST + j0] = w3;
        if (b == 0) {
            *(float4*)&ws[WS_ABAR + (i0 + 0) * NS + j0] = w0;
            *(float4*)&ws[WS_ABAR + (i0 + 1) * NS + j0] = w1;
            *(float4*)&ws[WS_ABAR + (i0 + 2) * NS + j0] = w2;
            *(float4*)&ws[WS_ABAR + (i0 + 3) * NS + j0] = w3;
        }
    }
    if (b == 1 && tid < 16)
        *(float4*)&ws[WS_BBAR + 4 * tid] = *(const float4*)&Mcol[NS * ST + 4 * tid];
    if (tid < NS) VT[tid * ST + 0] = Mcol[NS * ST + tid];
    __syncthreads();

    // 6 levels of squaring with vs-expansion.
    float *cm = Mrow, *cmt = Mcol, *nm = Nrow, *nmt = Ncol;
    for (int s = 1; s <= 6; ++s) {
        if (s <= 4) {
            mm_sq42(cm, cmt, nm, nmt, tid);
            const int mexp = 1 << (s - 1);   // 1,2,4,8 = nj
            if (tid < 16 * mexp) {
                vs_expand1(cmt, VT, tid & 15, tid >> 4, mexp);
            }
        } else if (tid < 256) {
            mm_square<true>(cm, cmt, nm, nmt, tid);
        } else {
            const int e = tid - 256;
            const int iq = e & 15;
            if (s == 5) {
                vs_expand1(cmt, VT, iq, e >> 4, 16);
            } else {
                // s == 6: 2 columns per thread (j0, j0+1)
                const int j0 = 2 * (e >> 4);
                const int i0 = 4 * iq;
                float4 c0 = {0,0,0,0}, c1 = {0,0,0,0};
#pragma unroll 8
                for (int k = 0; k < NS; ++k) {
                    float4 av = *(const float4*)&cmt[k * ST + i0];
                    float2 bv = *(const float2*)&VT[k * ST + j0];
                    c0.x += av.x * bv.x; c0.y += av.y * bv.x;
                    c0.z += av.z * bv.x; c0.w += av.w * bv.x;
                    c1.x += av.x * bv.y; c1.y += av.y * bv.y;
                    c1.z += av.z * bv.y; c1.w += av.w * bv.y;
                }
                float2 w0 = {c0.x, c1.x}, w1 = {c0.y, c1.y};
                float2 w2 = {c0.z, c1.z}, w3 = {c0.w, c1.w};
                *(float2*)&VT[(i0 + 0) * ST + 32 + j0] = w0;
                *(float2*)&VT[(i0 + 1) * ST + 32 + j0] = w1;
                *(float2*)&VT[(i0 + 2) * ST + 32 + j0] = w2;
                *(float2*)&VT[(i0 + 3) * ST + 32 + j0] = w3;
            }
        }
        __syncthreads();
        { float* t = cm; cm = nm; nm = t; t = cmt; cmt = nmt; nmt = t; }
        if (s == 4 && b == 2) {   // cm == A^16
            for (int o = tid; o < (NS * NS) / 4; o += 512) {
                int r = o >> 4, c4 = (o & 15) * 4;
                *(float4*)&ws[WS_A16 + r * NS + c4] = *(const float4*)&cm[r * ST + c4];
            }
        }
    }
    // (Mrow, Mcol) = A^64 pair; (Nrow, Ncol) = A^32 (dead).

    // Phase A: waves 0-3: VT -> vsS transpose (+ b3 VS store).
    //          waves 4-7: A^128 square (M-pair -> N-pair, both layouts kept).
    if (tid < 256) {
        const int i0 = 4 * (tid >> 4), j0 = 4 * (tid & 15);
        float4 v0 = *(const float4*)&VT[(i0 + 0) * ST + j0];
        float4 v1 = *(const float4*)&VT[(i0 + 1) * ST + j0];
        float4 v2 = *(const float4*)&VT[(i0 + 2) * ST + j0];
        float4 v3 = *(const float4*)&VT[(i0 + 3) * ST + j0];
        float4 w0 = {v0.x, v1.x, v2.x, v3.x};
        float4 w1 = {v0.y, v1.y, v2.y, v3.y};
        float4 w2 = {v0.z, v1.z, v2.z, v3.z};
        float4 w3 = {v0.w, v1.w, v2.w, v3.w};
        *(float4*)&vsS[(j0 + 0) * NS + i0] = w0;
        *(float4*)&vsS[(j0 + 1) * NS + i0] = w1;
        *(float4*)&vsS[(j0 + 2) * NS + i0] = w2;
        *(float4*)&vsS[(j0 + 3) * NS + i0] = w3;
        if (b == 3) {
            *(float4*)&ws[WS_VS + (j0 + 0) * NS + i0] = w0;
            *(float4*)&ws[WS_VS + (j0 + 1) * NS + i0] = w1;
            *(float4*)&ws[WS_VS + (j0 + 2) * NS + i0] = w2;
            *(float4*)&ws[WS_VS + (j0 + 3) * NS + i0] = w3;
        }
    } else {
        mm_square<true>(Mrow, Mcol, Nrow, Ncol, tid - 256);   // A^128
    }
    __syncthreads();

    // Phase B: waves 0-3: xle[m][i] = sum_j vs[j][i] * uT[j][m].
    //          waves 4-7: A^256 square, rows only -> VT (VT dead).
    if (tid < 256) {
        const int ig = tid & 15, mg = tid >> 4;
        float4 a0 = {0,0,0,0}, a1 = {0,0,0,0}, a2 = {0,0,0,0}, a3 = {0,0,0,0};
#pragma unroll 4
        for (int j = 0; j < NS; j += 2) {
            float4 am  = *(const float4*)&uT[j * ST + 4 * mg];
            float4 bi  = *(const float4*)&vsS[j * NS + 4 * ig];
            float4 am2 = *(const float4*)&uT[(j + 1) * ST + 4 * mg];
            float4 bi2 = *(const float4*)&vsS[(j + 1) * NS + 4 * ig];
            FMA44(am, bi)
            FMA44(am2, bi2)
        }
        *(float4*)&xleS[(4 * mg + 0) * NS + 4 * ig] = a0;
        *(float4*)&xleS[(4 * mg + 1) * NS + 4 * ig] = a1;
        *(float4*)&xleS[(4 * mg + 2) * NS + 4 * ig] = a2;
        *(float4*)&xleS[(4 * mg + 3) * NS + 4 * ig] = a3;
    } else {
        mm_square<false>(Nrow, Ncol, VT, VT, tid - 256);      // A^256 rows
    }
    __syncthreads();

    // Phase C1: P[g] = A64*xle_{4g} + xle_{4g+1}  (waves 0-3)
    //           Q[g] = A64*xle_{4g+2} + xle_{4g+3} (waves 4-7)
    // tid<64 inits scan state (stash=uT is dead).
    if (tid < 256) pq_step(Mcol, xleS, HbP, 0, tid);
    else           pq_step(Mcol, xleS, HbQ, 2, tid - 256);
    if (tid < 64) { xcS[tid] = 0.f; stash[tid] = 0.f; }   // Z_0 = X0_0 = 0
    __syncthreads();

    // Phase C2: Y[g] = A128*P[g] + Q[g] on all 512 threads (float2 tiles).
    y_step512(Ncol, HbP, HbQ, HbY, tid);
    __syncthreads();

    // Phase D: 15-step serial scan  Z_{g+1} = A256 * Z_g + Y_g.
    // SINGLE WAVE: lane i holds row i of A^256 in 16 float4 regs; xc is read
    // from xcS via uniform (broadcast, conflict-free) float4 loads; Y vectors
    // preloaded into registers. No barriers in the loop.
    if (tid < 64) {
        const int i = tid;
        float4 arow[16];
#pragma unroll
        for (int c = 0; c < 16; ++c)
            arow[c] = *(const float4*)&VT[i * ST + 4 * c];
        float yv[15];
#pragma unroll
        for (int g = 0; g < 15; ++g) yv[g] = HbY[g * ST + i];
        for (int g = 0; g < 15; ++g) {
            float a0 = 0.f, a1 = 0.f, a2 = 0.f, a3 = 0.f;
#pragma unroll
            for (int c = 0; c < 16; ++c) {
                float4 xv = *(const float4*)&xcS[4 * c];
                a0 = fmaf(arow[c].x, xv.x, a0);
                a1 = fmaf(arow[c].y, xv.y, a1);
                a2 = fmaf(arow[c].z, xv.z, a2);
                a3 = fmaf(arow[c].w, xv.w, a3);
            }
            const float xn = ((a0 + a1) + (a2 + a3)) + yv[g];
            xcS[i] = xn;                       // next iter reads via broadcast
            stash[(4 * g + 4) * ST + i] = xn;  // X0_{4(g+1)} (fire-and-forget)
        }
    }
    __syncthreads();

    // Phase E1: stash[4g+1] = A64*stash[4g] + xle_{4g}      (waves 0-3)
    //           stash[4g+2] = A128*stash[4g] + P[g]         (waves 4-7)
    if (tid < 256) inner_step(Mcol, xleS, stash, 1, tid);
    else           e1u_step(Ncol, HbP, stash, tid - 256);
    __syncthreads();

    // Phase E2: stash[4g+3] = A64*stash[4g+2] + xle_{4g+2}  (all 512, float2)
    inner512(Mcol, xleS, stash, 3, tid);
    __syncthreads();

    // Phase F: bulk-store X0 (single drain at kernel end)
    {
        const int m = tid >> 3, t8 = (tid & 7) * 8;
        float4 o1 = *(const float4*)&stash[m * ST + t8];
        float4 o2 = *(const float4*)&stash[m * ST + t8 + 4];
        *(float4*)&out[X0_IDX(b, m) + t8]     = o1;
        *(float4*)&out[X0_IDX(b, m) + t8 + 4] = o2;
    }
}

// ---------------------------------------------------------------------------
// K2: main, 2-CHUNK blocks. Block (mq, b) processes chunks m = 2mq, 2mq+1:
// matrices (ABAR regs, A16, VS, D) staged ONCE, phase-1 run twice (X into
// Xl / Xl2), C^T staged ONCE, GEMM twice. Blocks 1024 -> 512; LDS 67.3 KB ->
// 2 blocks/CU (all 512 co-resident in one pass).
// ---------------------------------------------------------------------------
__global__ __launch_bounds__(256) void k_main2(const float* __restrict__ u,
                                               const float* __restrict__ Cm,
                                               const float* __restrict__ Dv,
                                               const float* __restrict__ ws,
                                               float* __restrict__ out) {
    __shared__ __align__(16) float Xl [NS * ST];    // A_bar staging, then X(chunk0)
    __shared__ __align__(16) float Xl2[NS * ST];    // X(chunk1)
    __shared__ __align__(16) float pool[NS * CP];   // phase1 scratch+A16, then C^T
    __shared__ float uS[2][SCH], DS[CH], bbS[NS];
    const int mq = blockIdx.x, b = blockIdx.y;
    const int m0 = 2 * mq;
    const int tid = threadIdx.x;
    const int l = tid & 63, w = tid >> 6;

    for (int o = tid; o < (NS * NS) / 4; o += 256) {
        int r = o >> 4, c4 = (o & 15) * 4;
        *(float4*)&Xl[r * ST + c4]           = *(const float4*)&ws[WS_ABAR + r * NS + c4];
        *(float4*)&pool[P_A16 + r * NS + c4] = *(const float4*)&ws[WS_A16 + r * NS + c4];
    }
    for (int o = tid; o < 16 * NS; o += 256) pool[P_VSS + o] = ws[WS_VS + o];
    if (tid < NS) {
        uS[0][tid] = u[b * LSEQ + (m0 + 0) * SCH + tid];
        uS[1][tid] = u[b * LSEQ + (m0 + 1) * SCH + tid];
        bbS[tid]   = ws[WS_BBAR + tid];
    }
    if (tid < CH) DS[tid] = Dv[tid];
    __syncthreads();

    // Row-per-lane A_bar: lane l holds row l (16 float4); survives Xl overwrite.
    float4 arow[16];
#pragma unroll
    for (int c = 0; c < 16; ++c)
        arow[c] = *(const float4*)&Xl[l * ST + 4 * c];
    const float bbl = bbS[l];
    float4 a16r[4];
#pragma unroll
    for (int kq = 0; kq < 4; ++kq)
        a16r[kq] = *(const float4*)&pool[P_A16 + l * NS + 16 * w + 4 * kq];

    for (int c = 0; c < 2; ++c) {
        const int m = m0 + c;
        float* const Xp = c ? Xl2 : Xl;

        // chunk-start: PLE (all threads) + X0 load (tid<64)
        {
            float s = 0.f;
#pragma unroll
            for (int j = 0; j < 16; ++j) s += pool[P_VSS + j * NS + l] * uS[c][16 * w + 15 - j];
            pool[P_PLE + w * NS + l] = s;
        }
        if (tid < NS) pool[P_XBS + tid] = out[X0_IDX(b, m) + tid];
        __syncthreads();

        // A^16 mini-scan (3 steps)
        for (int p = 1; p < 4; ++p) {
            float4 x0q = *(const float4*)&pool[P_XBS + (p - 1) * NS + 16 * w + 0];
            float4 x1q = *(const float4*)&pool[P_XBS + (p - 1) * NS + 16 * w + 4];
            float4 x2q = *(const float4*)&pool[P_XBS + (p - 1) * NS + 16 * w + 8];
            float4 x3q = *(const float4*)&pool[P_XBS + (p - 1) * NS + 16 * w + 12];
            float s = a16r[0].x * x0q.x + a16r[0].y * x0q.y + a16r[0].z * x0q.z + a16r[0].w * x0q.w
                    + a16r[1].x * x1q.x + a16r[1].y * x1q.y + a16r[1].z * x1q.z + a16r[1].w * x1q.w
                    + a16r[2].x * x2q.x + a16r[2].y * x2q.y + a16r[2].z * x2q.z + a16r[2].w * x2q.w
                    + a16r[3].x * x3q.x + a16r[3].y * x3q.y + a16r[3].z * x3q.z + a16r[3].w * x3q.w;
            pool[P_PART + w * NS + l] = s;
            __syncthreads();
            if (w == 0) {
                float xn = pool[P_PART + l] + pool[P_PART + NS + l] + pool[P_PART + 2 * NS + l]
                         + pool[P_PART + 3 * NS + l] + pool[P_PLE + (p - 1) * NS + l];
                pool[P_XBS + p * NS + l] = xn;
            }
            __syncthreads();
        }

        // Within-paragraph recurrence, row-per-lane (wave-private LDS slice).
        float ur[16];
#pragma unroll
        for (int s = 0; s < 16; ++s) ur[s] = uS[c][16 * w + s];
        pool[P_XCW + w * NS + l] = pool[P_XBS + w * NS + l];
        for (int s = 0; s < 16; ++s) {
            const int t = 16 * w + s;
            float a0 = 0.f, a1 = 0.f, a2 = 0.f, a3 = 0.f;
#pragma unroll
            for (int cc = 0; cc < 16; ++cc) {
                float4 xv = *(const float4*)&pool[P_XCW + w * NS + 4 * cc];  // broadcast
                a0 = fmaf(arow[cc].x, xv.x, a0);
                a1 = fmaf(arow[cc].y, xv.y, a1);
                a2 = fmaf(arow[cc].z, xv.z, a2);
                a3 = fmaf(arow[cc].w, xv.w, a3);
            }
            const float xn = ((a0 + a1) + (a2 + a3)) + bbl * ur[s];
            pool[P_XCW + w * NS + l] = xn;    // next iter reads via broadcast
            Xp[l * ST + t] = xn;
        }
        __syncthreads();   // protect P_* scratch before next chunk reuses it
    }

    // stage C^T over the whole pool (stride 128) — ONCE for both chunks
#pragma unroll
    for (int rep = 0; rep < 8; ++rep) {
        const int ii = tid & 63;
        const int cg = (tid >> 6) + 4 * rep;   // 0..31
        float4 v;
        v.x = Cm[(4 * cg + 0) * NS + ii];
        v.y = Cm[(4 * cg + 1) * NS + ii];
        v.z = Cm[(4 * cg + 2) * NS + ii];
        v.w = Cm[(4 * cg + 3) * NS + ii];
        *(float4*)&pool[ii * CP + 4 * cg] = v;
    }
    __syncthreads();

    // GEMM for both chunks (C^T and Xl/Xl2 both resident)
    for (int c = 0; c < 2; ++c) {
        const float* const Xp = c ? Xl2 : Xl;
        const int tg = tid & 7, cq = tid >> 3;   // t0 = 8*tg, c0 = 4*cq
        float acc[4][8];
#pragma unroll
        for (int r = 0; r < 4; ++r)
#pragma unroll
            for (int cc = 0; cc < 8; ++cc) acc[r][cc] = 0.f;
#pragma unroll 4
        for (int ii = 0; ii < NS; ++ii) {
            float4 cv = *(const float4*)&pool[ii * CP + 4 * cq];
            float4 xa = *(const float4*)&Xp[ii * ST + 8 * tg + 0];
            float4 xb = *(const float4*)&Xp[ii * ST + 8 * tg + 4];
            float cr[4] = {cv.x, cv.y, cv.z, cv.w};
            float xv[8] = {xa.x, xa.y, xa.z, xa.w, xb.x, xb.y, xb.z, xb.w};
#pragma unroll
            for (int r = 0; r < 4; ++r)
#pragma unroll
                for (int cc = 0; cc < 8; ++cc) acc[r][cc] += cr[r] * xv[cc];
        }
        const size_t obase = ((size_t)b * CH) * LSEQ + (size_t)(m0 + c) * SCH + 8 * tg;
#pragma unroll
        for (int r = 0; r < 4; ++r) {
            const int ch = 4 * cq + r;
            const float dv = DS[ch];
            float4 o1, o2;
            o1.x = acc[r][0] + dv * uS[c][8 * tg + 0];
            o1.y = acc[r][1] + dv * uS[c][8 * tg + 1];
            o1.z = acc[r][2] + dv * uS[c][8 * tg + 2];
            o1.w = acc[r][3] + dv * uS[c][8 * tg + 3];
            o2.x = acc[r][4] + dv * uS[c][8 * tg + 4];
            o2.y = acc[r][5] + dv * uS[c][8 * tg + 5];
            o2.z = acc[r][6] + dv * uS[c][8 * tg + 6];
            o2.w = acc[r][7] + dv * uS[c][8 * tg + 7];
            float* op = out + obase + (size_t)ch * LSEQ;
            *(float4*)(op)     = o1;
            *(float4*)(op + 4) = o2;
        }
    }
}

extern "C" void kernel_launch(void* const* d_in, const int* in_sizes, int n_in,
                              void* d_out, int out_size, void* d_ws, size_t ws_size,
                              hipStream_t stream) {
    const float* u   = (const float*)d_in[0];
    const float* A   = (const float*)d_in[1];
    const float* Bv  = (const float*)d_in[2];
    const float* Cm  = (const float*)d_in[3];
    const float* Dv  = (const float*)d_in[4];
    const float* dtp = (const float*)d_in[5];
    float* ws  = (float*)d_ws;
    float* out = (float*)d_out;

    k_sb<<<NB, 512, 0, stream>>>(u, A, Bv, dtp, ws, out);
    k_main2<<<dim3(MCH / 2, NB), 256, 0, stream>>>(u, Cm, Dv, ws, out);
}